// Round 8
// baseline (605.313 us; speedup 1.0000x reference)
//
#include <hip/hip_runtime.h>

#define DECAY 0.99f
#define OMD   0.01f
#define EPS   1e-5f

constexpr int Bb = 16, Ss = 2048, Dd = 512, Kk = 2048;
constexpr int Nn = Bb * Ss;  // 32768

typedef __attribute__((ext_vector_type(8))) short short8;
typedef __attribute__((ext_vector_type(4))) float f32x4;

__device__ __forceinline__ unsigned short f2bf(float x) {
    unsigned u = __float_as_uint(x);
    unsigned r = (u + 0x7FFFu + ((u >> 16) & 1u)) >> 16;   // RN-even
    return (unsigned short)r;
}
__device__ __forceinline__ float bf2f(unsigned short u) {
    return __uint_as_float((unsigned)u << 16);
}

__device__ __forceinline__ void gload_lds16(const void* g, void* l) {
    __builtin_amdgcn_global_load_lds(
        (const __attribute__((address_space(1))) void*)g,
        (__attribute__((address_space(3))) void*)l, 16, 0, 0);
}

#define BARRIER() do { asm volatile("" ::: "memory"); \
                       __builtin_amdgcn_s_barrier();  \
                       asm volatile("" ::: "memory"); } while (0)

// ---------------- row sum-of-squares ---------------------------------------
__global__ void rows_sq(const float* __restrict__ in, float* __restrict__ out, int nrows) {
    int row  = blockIdx.x * 4 + (threadIdx.x >> 6);
    int lane = threadIdx.x & 63;
    if (row >= nrows) return;
    const float4* p = (const float4*)(in + (size_t)row * Dd);
    float s = 0.f;
    #pragma unroll
    for (int i = 0; i < 2; ++i) {
        float4 v = p[lane + 64 * i];
        s += v.x * v.x + v.y * v.y + v.z * v.z + v.w * v.w;
    }
    #pragma unroll
    for (int off = 32; off; off >>= 1) s += __shfl_down(s, off);
    if (lane == 0) out[row] = s;
}

// ---------------- fp32 -> bf16x3 split -------------------------------------
__global__ void conv_split(const float* __restrict__ in,
                           unsigned short* __restrict__ ph,
                           unsigned short* __restrict__ pm,
                           unsigned short* __restrict__ pl, int n4) {
    int i = blockIdx.x * 256 + threadIdx.x;
    if (i >= n4) return;
    float4 v = ((const float4*)in)[i];
    float f[4] = {v.x, v.y, v.z, v.w};
    ushort4 h, m, l;
    unsigned short hh[4], mm[4], ll[4];
    #pragma unroll
    for (int j = 0; j < 4; ++j) {
        float x = f[j];
        unsigned short a = f2bf(x);  float ra = x - bf2f(a);
        unsigned short b = f2bf(ra); float rb = ra - bf2f(b);
        unsigned short c = f2bf(rb);
        hh[j] = a; mm[j] = b; ll[j] = c;
    }
    h.x = hh[0]; h.y = hh[1]; h.z = hh[2]; h.w = hh[3];
    m.x = mm[0]; m.y = mm[1]; m.z = mm[2]; m.w = mm[3];
    l.x = ll[0]; l.y = ll[1]; l.z = ll[2]; l.w = ll[3];
    ((ushort4*)ph)[i] = h;
    ((ushort4*)pm)[i] = m;
    ((ushort4*)pl)[i] = l;
}

// ---------------- bf16x3 MFMA GEMM, 256x256 tile, race-free 8-phase --------
// K_eff = 3072 -> 48 K-tiles of BK=64, 24 iters x 2 tiles (buf0 even, buf1 odd).
// Slot deaths: buf0.B ph1, buf0.A ph2, buf1.B ph5, buf1.A ph6.  One stage
// (2 gloads) per phase: ph0:A1lo(t+1) ph1:A1hi(t+1) ph2:B0lo(t+2)
// ph3:B0hi(t+2) ph4:A0lo(t+2) ph5:A0hi(t+2) ph6:B1lo(t+3) ph7:B1hi(t+3).
// vmcnt(4)@ph3 covers buf1(t+1); vmcnt(4)@ph7 covers buf0(t+2). Min lead 3 ph.
__global__ __launch_bounds__(512, 1) void gemm_split256(
    const unsigned short* __restrict__ xp,   // [3][Nn][512] bf16 planes
    const unsigned short* __restrict__ ep,   // [3][Kk][512]
    const float* __restrict__ xsq,
    const float* __restrict__ esq,
    float* __restrict__ dist,                // [Nn, Kk]
    unsigned long long* __restrict__ packed) // [Nn] argmax accumulator
{
    __shared__ unsigned short As[2][256][64];   // 64 KB
    __shared__ unsigned short Bs[2][256][64];   // 64 KB

    const int tid  = threadIdx.x;
    const int lane = tid & 63;
    const int wid  = tid >> 6;
    const int wr   = wid >> 2;   // 0..1  (M, 128 rows each)
    const int wc   = wid & 3;    // 0..3  (N, 64 cols each)

    // XCD-aware swizzle (nwg = 1024, divisible by 8 -> bijective)
    int bid = blockIdx.x;
    int wg  = (bid & 7) * 128 + (bid >> 3);
    int mb  = wg >> 3, nb = wg & 7;
    const int row0 = mb * 256, col0 = nb * 256;

    f32x4 acc[8][4] = {};
    short8 af[4], afh[4], bl[2], blh[2], bh[2], bhh[2];

    const int l8   = lane >> 3;          // 0..7
    const int csrc = (lane & 7) ^ l8;    // pre-swizzled source chunk

    // plane selection (ternaries -> cselect; p=6 (overrun tiles) -> plane 0, valid)
    auto Aplane = [&](int tt) -> const unsigned short* {
        int p = tt >> 3;   // A parts: h,h,m,m,h,l
        size_t off = (p == 2 || p == 3) ? 1 : (p == 5) ? 2 : 0;
        return xp + off * ((size_t)Nn * Dd);
    };
    auto Bplane = [&](int tt) -> const unsigned short* {
        int p = tt >> 3;   // B parts: h,m,h,m,l,h
        size_t off = (p == 1 || p == 3) ? 1 : (p == 4) ? 2 : 0;
        return ep + off * ((size_t)Kk * Dd);
    };

    // stage one 128-row half (2 gloads/thread = 16 KB)
    auto stageA = [&](int d, int half, const unsigned short* pl, int ko) {
        #pragma unroll
        for (int jj = 0; jj < 2; ++jj) {
            int rowbase = half * 128 + jj * 64 + wid * 8;
            const unsigned short* src =
                pl + (size_t)(row0 + rowbase + l8) * Dd + ko + csrc * 8;
            gload_lds16(src, &As[d][rowbase][0]);
        }
    };
    auto stageB = [&](int d, int half, const unsigned short* pl, int ko) {
        #pragma unroll
        for (int jj = 0; jj < 2; ++jj) {
            int rowbase = half * 128 + jj * 64 + wid * 8;
            const unsigned short* src =
                pl + (size_t)(col0 + rowbase + l8) * Dd + ko + csrc * 8;
            gload_lds16(src, &Bs[d][rowbase][0]);
        }
    };

    auto readA = [&](int d, int msel) {
        #pragma unroll
        for (int m = 0; m < 4; ++m) {
            int r  = wr * 128 + (msel * 4 + m) * 16 + (lane & 15);
            int c  = ((lane >> 4))     ^ (r & 7);
            int c2 = ((lane >> 4) + 4) ^ (r & 7);
            af[m]  = *(const short8*)&As[d][r][c * 8];
            afh[m] = *(const short8*)&As[d][r][c2 * 8];
        }
    };
    auto readBlo = [&](int d) {
        #pragma unroll
        for (int n = 0; n < 2; ++n) {
            int r  = wc * 64 + n * 16 + (lane & 15);
            int c  = ((lane >> 4))     ^ (r & 7);
            int c2 = ((lane >> 4) + 4) ^ (r & 7);
            bl[n]  = *(const short8*)&Bs[d][r][c * 8];
            blh[n] = *(const short8*)&Bs[d][r][c2 * 8];
        }
    };
    auto readBhi = [&](int d) {
        #pragma unroll
        for (int n = 0; n < 2; ++n) {
            int r  = wc * 64 + (2 + n) * 16 + (lane & 15);
            int c  = ((lane >> 4))     ^ (r & 7);
            int c2 = ((lane >> 4) + 4) ^ (r & 7);
            bh[n]  = *(const short8*)&Bs[d][r][c * 8];
            bhh[n] = *(const short8*)&Bs[d][r][c2 * 8];
        }
    };

    auto mfmaQ = [&](int msel, int nsel, const short8* b0, const short8* b1) {
        __builtin_amdgcn_s_setprio(1);
        #pragma unroll
        for (int m = 0; m < 4; ++m)
            #pragma unroll
            for (int n = 0; n < 2; ++n) {
                int am = msel * 4 + m, bn = nsel * 2 + n;
                acc[am][bn] = __builtin_amdgcn_mfma_f32_16x16x32_bf16(af[m], b0[n], acc[am][bn], 0, 0, 0);
            }
        #pragma unroll
        for (int m = 0; m < 4; ++m)
            #pragma unroll
            for (int n = 0; n < 2; ++n) {
                int am = msel * 4 + m, bn = nsel * 2 + n;
                acc[am][bn] = __builtin_amdgcn_mfma_f32_16x16x32_bf16(afh[m], b1[n], acc[am][bn], 0, 0, 0);
            }
        __builtin_amdgcn_s_setprio(0);
    };

    // prologue: mirror steady-state prev-S3..S8: buf0{Blo,Bhi,Alo,Ahi}(t0),
    // buf1{Blo,Bhi}(t1). vmcnt(4) completes buf0 tile0; buf1.B stays in flight.
    stageB(0, 0, Bplane(0), 0);
    stageB(0, 1, Bplane(0), 0);
    stageA(0, 0, Aplane(0), 0);
    stageA(0, 1, Aplane(0), 0);
    stageB(1, 0, Bplane(1), 64);
    stageB(1, 1, Bplane(1), 64);
    asm volatile("s_waitcnt vmcnt(4)" ::: "memory");
    BARRIER();

    for (int i = 0; i < 24; ++i) {
        const int t = 2 * i;
        const unsigned short* Ap1 = Aplane(t + 1);
        const unsigned short* Ap2 = Aplane(t + 2);
        const unsigned short* Bp2 = Bplane(t + 2);
        const unsigned short* Bp3 = Bplane(t + 3);
        const int ko1 = ((t + 1) & 7) * 64;
        const int ko2 = ((t + 2) & 7) * 64;
        const int ko3 = ((t + 3) & 7) * 64;

        // ---- ph0: tile t Q(0,0); stage buf1.Alo(t+1) [buf1.A dead since prev ph6]
        readA(0, 0); readBlo(0);
        stageA(1, 0, Ap1, ko1);
        asm volatile("s_waitcnt lgkmcnt(8)" ::: "memory");
        BARRIER(); mfmaQ(0, 0, bl, blh); BARRIER();
        // ---- ph1: Q(0,1); stage buf1.Ahi(t+1)
        readBhi(0);
        stageA(1, 1, Ap1, ko1);
        BARRIER(); mfmaQ(0, 1, bh, bhh); BARRIER();
        // ---- ph2: Q(1,1); stage buf0.Blo(t+2) [buf0.B dead since ph1]
        readA(0, 1);
        stageB(0, 0, Bp2, ko2);
        BARRIER(); mfmaQ(1, 1, bh, bhh); BARRIER();
        // ---- ph3: Q(1,0) (B-lo held in regs); stage buf0.Bhi(t+2); vmcnt(4)
        stageB(0, 1, Bp2, ko2);
        BARRIER(); mfmaQ(1, 0, bl, blh);
        asm volatile("s_waitcnt vmcnt(4)" ::: "memory");   // buf1(t+1) landed
        BARRIER();
        // ---- ph4: tile t+1 Q(0,0); stage buf0.Alo(t+2) [buf0.A dead since ph2]
        readA(1, 0); readBlo(1);
        stageA(0, 0, Ap2, ko2);
        asm volatile("s_waitcnt lgkmcnt(8)" ::: "memory");
        BARRIER(); mfmaQ(0, 0, bl, blh); BARRIER();
        // ---- ph5: Q(0,1); stage buf0.Ahi(t+2)
        readBhi(1);
        stageA(0, 1, Ap2, ko2);
        BARRIER(); mfmaQ(0, 1, bh, bhh); BARRIER();
        // ---- ph6: Q(1,1); stage buf1.Blo(t+3) [buf1.B dead since ph5]
        readA(1, 1);
        stageB(1, 0, Bp3, ko3);
        BARRIER(); mfmaQ(1, 1, bh, bhh); BARRIER();
        // ---- ph7: Q(1,0); stage buf1.Bhi(t+3); vmcnt(4)
        stageB(1, 1, Bp3, ko3);
        BARRIER(); mfmaQ(1, 0, bl, blh);
        asm volatile("s_waitcnt vmcnt(4)" ::: "memory");   // buf0(t+2) landed
        BARRIER();
    }
    asm volatile("s_waitcnt vmcnt(0)" ::: "memory");

    // epilogue: dist = 2*dot - xsq - esq ; fused per-row argmax
    const int jrow = (lane >> 4) * 4;
    const int ncol = lane & 15;
    #pragma unroll
    for (int m = 0; m < 8; ++m) {
        int rbase = row0 + wr * 128 + m * 16 + jrow;
        #pragma unroll
        for (int j = 0; j < 4; ++j) {
            int row = rbase + j;
            float xs = xsq[row];
            float best = -3.4e38f; int bi = 0;
            #pragma unroll
            for (int n = 0; n < 4; ++n) {
                int col = col0 + wc * 64 + n * 16 + ncol;
                float v = 2.f * acc[m][n][j] - xs - esq[col];
                dist[(size_t)row * Kk + col] = v;
                if (v > best) { best = v; bi = col; }
            }
            unsigned u = __float_as_uint(best);
            u = (u & 0x80000000u) ? ~u : (u | 0x80000000u);
            unsigned long long pk = ((unsigned long long)u << 32) | (unsigned)(~bi);
            #pragma unroll
            for (int off = 1; off < 16; off <<= 1) {
                unsigned long long o = __shfl_xor(pk, off);
                if (o > pk) pk = o;
            }
            if (ncol == 0) atomicMax(&packed[row], pk);
        }
    }
}

__global__ void unpack_argmax(const unsigned long long* __restrict__ packed,
                              float* __restrict__ ind_f, int* __restrict__ ind_i) {
    int i = blockIdx.x * 256 + threadIdx.x;
    unsigned long long p = packed[i];
    int k = (int)(~(unsigned)(p & 0xFFFFFFFFull));
    ind_f[i] = (float)k;
    ind_i[i] = k;
}

// ---------------- OLD fp32 GEMM (fallback when ws too small) ---------------
#define BM 64
#define BN 64
#define BK 32
__global__ __launch_bounds__(256) void gemm_dist(
    const float* __restrict__ A, const float* __restrict__ Bm,
    const float* __restrict__ xsq, const float* __restrict__ esq,
    float* __restrict__ dist)
{
    __shared__ float Asl[BK][BM + 4];
    __shared__ float Bsl[BK][BN + 4];
    int tid = threadIdx.x;
    int row0 = blockIdx.x * BM, col0 = blockIdx.y * BN;
    int tx = tid & 15, ty = tid >> 4;
    float acc[4][4] = {};
    int lr = tid >> 3, lc = (tid & 7) * 4;
    for (int d0 = 0; d0 < Dd; d0 += BK) {
        float4 a0 = *(const float4*)(A  + (size_t)(row0 + lr)      * Dd + d0 + lc);
        float4 a1 = *(const float4*)(A  + (size_t)(row0 + lr + 32) * Dd + d0 + lc);
        float4 b0 = *(const float4*)(Bm + (size_t)(col0 + lr)      * Dd + d0 + lc);
        float4 b1 = *(const float4*)(Bm + (size_t)(col0 + lr + 32) * Dd + d0 + lc);
        __syncthreads();
        Asl[lc + 0][lr] = a0.x; Asl[lc + 1][lr] = a0.y; Asl[lc + 2][lr] = a0.z; Asl[lc + 3][lr] = a0.w;
        Asl[lc + 0][lr + 32] = a1.x; Asl[lc + 1][lr + 32] = a1.y; Asl[lc + 2][lr + 32] = a1.z; Asl[lc + 3][lr + 32] = a1.w;
        Bsl[lc + 0][lr] = b0.x; Bsl[lc + 1][lr] = b0.y; Bsl[lc + 2][lr] = b0.z; Bsl[lc + 3][lr] = b0.w;
        Bsl[lc + 0][lr + 32] = b1.x; Bsl[lc + 1][lr + 32] = b1.y; Bsl[lc + 2][lr + 32] = b1.z; Bsl[lc + 3][lr + 32] = b1.w;
        __syncthreads();
        #pragma unroll
        for (int kd = 0; kd < BK; ++kd) {
            float4 av = *(const float4*)&Asl[kd][ty * 4];
            float4 bv = *(const float4*)&Bsl[kd][tx * 4];
            float a[4] = {av.x, av.y, av.z, av.w};
            float b[4] = {bv.x, bv.y, bv.z, bv.w};
            #pragma unroll
            for (int i = 0; i < 4; ++i)
                #pragma unroll
                for (int j = 0; j < 4; ++j)
                    acc[i][j] = fmaf(a[i], b[j], acc[i][j]);
        }
    }
    #pragma unroll
    for (int i = 0; i < 4; ++i) {
        int row = row0 + ty * 4 + i;
        float xs = xsq[row];
        float4 o;
        int col = col0 + tx * 4;
        o.x = 2.f * acc[i][0] - xs - esq[col + 0];
        o.y = 2.f * acc[i][1] - xs - esq[col + 1];
        o.z = 2.f * acc[i][2] - xs - esq[col + 2];
        o.w = 2.f * acc[i][3] - xs - esq[col + 3];
        *(float4*)(dist + (size_t)row * Kk + col) = o;
    }
}

__global__ void argmax_k(const float* __restrict__ dist,
                         float* __restrict__ ind_f, int* __restrict__ ind_i) {
    int row  = blockIdx.x * 4 + (threadIdx.x >> 6);
    int lane = threadIdx.x & 63;
    const float4* p = (const float4*)(dist + (size_t)row * Kk);
    float best = -3.4e38f;
    int bidx = 0;
    #pragma unroll
    for (int it = 0; it < Kk / 4 / 64; ++it) {
        int i = lane + it * 64;
        float4 v = p[i];
        int base = i * 4;
        if (v.x > best) { best = v.x; bidx = base + 0; }
        if (v.y > best) { best = v.y; bidx = base + 1; }
        if (v.z > best) { best = v.z; bidx = base + 2; }
        if (v.w > best) { best = v.w; bidx = base + 3; }
    }
    #pragma unroll
    for (int off = 32; off; off >>= 1) {
        float ov = __shfl_down(best, off);
        int   oi = __shfl_down(bidx, off);
        if (ov > best || (ov == best && oi < bidx)) { best = ov; bidx = oi; }
    }
    if (lane == 0) { ind_f[row] = (float)bidx; ind_i[row] = bidx; }
}

// ---------------- quantize gather + segment-sum scatter --------------------
__global__ void gather_scatter(const float* __restrict__ x,
                               const float* __restrict__ embed,
                               const int* __restrict__ ind,
                               float* __restrict__ quant,
                               float* __restrict__ esum,
                               int* __restrict__ bins) {
    int n = blockIdx.x;
    int k = ind[n];
    int t = threadIdx.x;
    size_t xb = (size_t)n * Dd;
    size_t eb = (size_t)k * Dd;
    float v0 = x[xb + t];
    float v1 = x[xb + t + 256];
    quant[xb + t]       = embed[eb + t];
    quant[xb + t + 256] = embed[eb + t + 256];
    atomicAdd(&esum[eb + t],       v0);
    atomicAdd(&esum[eb + t + 256], v1);
    if (t == 0) atomicAdd(&bins[k], 1);
}

// ---------------- EMA cluster size + laplace total -------------------------
__global__ void finalize1(const float* __restrict__ cs, const int* __restrict__ bins,
                          float* __restrict__ ncs, float* __restrict__ total_ws) {
    __shared__ float red[16];
    int t = threadIdx.x;
    float s = 0.f;
    for (int k = t; k < Kk; k += 1024) {
        float v = cs[k] * DECAY + OMD * (float)bins[k];
        ncs[k] = v;
        s += v;
    }
    #pragma unroll
    for (int off = 32; off; off >>= 1) s += __shfl_down(s, off);
    if ((t & 63) == 0) red[t >> 6] = s;
    __syncthreads();
    if (t == 0) {
        float tot = 0.f;
        #pragma unroll
        for (int i = 0; i < 16; ++i) tot += red[i];
        total_ws[0] = tot;
    }
}

// ---------------- EMA embed_avg + smoothed divide ---------------------------
__global__ void finalize2(const float* __restrict__ ea, const float* __restrict__ esum,
                          const float* __restrict__ ncs, const float* __restrict__ total_ws,
                          float* __restrict__ nea, float* __restrict__ ne) {
    int idx = blockIdx.x * 256 + threadIdx.x;
    float total = total_ws[0];
    int k = idx >> 7;
    float sm = (ncs[k] + EPS) / (total + Kk * EPS) * total;
    float inv = 1.f / sm;
    float4 a = ((const float4*)ea)[idx];
    float4 s = ((const float4*)esum)[idx];
    float4 r;
    r.x = a.x * DECAY + OMD * s.x;
    r.y = a.y * DECAY + OMD * s.y;
    r.z = a.z * DECAY + OMD * s.z;
    r.w = a.w * DECAY + OMD * s.w;
    ((float4*)nea)[idx] = r;
    float4 e;
    e.x = r.x * inv; e.y = r.y * inv; e.z = r.z * inv; e.w = r.w * inv;
    ((float4*)ne)[idx] = e;
}

extern "C" void kernel_launch(void* const* d_in, const int* in_sizes, int n_in,
                              void* d_out, int out_size, void* d_ws, size_t ws_size,
                              hipStream_t stream) {
    const float* x     = (const float*)d_in[0];
    const float* embed = (const float*)d_in[1];
    const float* cs    = (const float*)d_in[2];
    const float* ea    = (const float*)d_in[3];

    float* out     = (float*)d_out;
    float* o_quant = out;
    float* o_ind   = o_quant + (size_t)Nn * Dd;
    float* o_dist  = o_ind + Nn;
    float* o_ncs   = o_dist + (size_t)Nn * Kk;
    float* o_nea   = o_ncs + Kk;
    float* o_ne    = o_nea + (size_t)Kk * Dd;

    // ---- ws layout ----
    size_t xp_elems = (size_t)3 * Nn * Dd;       // bf16
    size_t ep_elems = (size_t)3 * Kk * Dd;
    char* w = (char*)d_ws;
    unsigned short* xp = (unsigned short*)w;                 w += xp_elems * 2;
    unsigned short* epp = (unsigned short*)w;                w += ep_elems * 2;
    float* xsq   = (float*)w;                                w += (size_t)Nn * 4;
    float* esq   = (float*)w;                                w += (size_t)Kk * 4;
    int*   ind_i = (int*)w;                                  w += (size_t)Nn * 4;
    int*   bins  = (int*)w;                                  w += (size_t)Kk * 4;
    float* esum  = (float*)w;                                w += (size_t)Kk * Dd * 4;
    unsigned long long* packed = (unsigned long long*)w;     w += (size_t)Nn * 8;
    float* total = (float*)w;                                w += 256;
    size_t need = (size_t)(w - (char*)d_ws);

    if (ws_size >= need) {
        hipMemsetAsync(bins, 0, (size_t)Kk * 4 + (size_t)Kk * Dd * 4 + (size_t)Nn * 8, stream);

        rows_sq<<<Nn / 4, 256, 0, stream>>>(x, xsq, Nn);
        rows_sq<<<Kk / 4, 256, 0, stream>>>(embed, esq, Kk);

        conv_split<<<(Nn * Dd / 4 + 255) / 256, 256, 0, stream>>>(
            x, xp, xp + (size_t)Nn * Dd, xp + (size_t)2 * Nn * Dd, Nn * Dd / 4);
        conv_split<<<(Kk * Dd / 4 + 255) / 256, 256, 0, stream>>>(
            embed, epp, epp + (size_t)Kk * Dd, epp + (size_t)2 * Kk * Dd, Kk * Dd / 4);

        gemm_split256<<<(Nn / 256) * (Kk / 256), 512, 0, stream>>>(
            xp, epp, xsq, esq, o_dist, packed);

        unpack_argmax<<<Nn / 256, 256, 0, stream>>>(packed, o_ind, ind_i);
    } else {
        float* fxsq  = (float*)d_ws;
        float* fesq  = fxsq + Nn;
        int*   find  = (int*)(fesq + Kk);
        int*   fbins = find + Nn;
        float* fesum = (float*)(fbins + Kk);
        float* ftot  = fesum + (size_t)Kk * Dd;
        xsq = fxsq; esq = fesq; ind_i = find; bins = fbins; esum = fesum; total = ftot;

        hipMemsetAsync(bins, 0, (size_t)(Kk + Kk * Dd) * sizeof(float), stream);
        rows_sq<<<Nn / 4, 256, 0, stream>>>(x, xsq, Nn);
        rows_sq<<<Kk / 4, 256, 0, stream>>>(embed, esq, Kk);
        dim3 g(Nn / BM, Kk / BN);
        gemm_dist<<<g, 256, 0, stream>>>(x, embed, xsq, esq, o_dist);
        argmax_k<<<Nn / 4, 256, 0, stream>>>(o_dist, o_ind, ind_i);
    }

    gather_scatter<<<Nn, 256, 0, stream>>>(x, embed, ind_i, o_quant, esum, bins);
    finalize1<<<1, 1024, 0, stream>>>(cs, bins, o_ncs, total);
    finalize2<<<(Kk * Dd / 4) / 256, 256, 0, stream>>>(ea, esum, o_ncs, total, o_nea, o_ne);
}

// Round 9
// 456.692 us; speedup vs baseline: 1.3254x; 1.3254x over previous
//
#include <hip/hip_runtime.h>

#define DECAY 0.99f
#define OMD   0.01f
#define EPS   1e-5f

constexpr int Bb = 16, Ss = 2048, Dd = 512, Kk = 2048;
constexpr int Nn = Bb * Ss;  // 32768

typedef __attribute__((ext_vector_type(8))) short short8;
typedef __attribute__((ext_vector_type(4))) float f32x4;

__device__ __forceinline__ unsigned short f2bf(float x) {
    unsigned u = __float_as_uint(x);
    unsigned r = (u + 0x7FFFu + ((u >> 16) & 1u)) >> 16;   // RN-even
    return (unsigned short)r;
}
__device__ __forceinline__ float bf2f(unsigned short u) {
    return __uint_as_float((unsigned)u << 16);
}

__device__ __forceinline__ void gload_lds16(const void* g, void* l) {
    __builtin_amdgcn_global_load_lds(
        (const __attribute__((address_space(1))) void*)g,
        (__attribute__((address_space(3))) void*)l, 16, 0, 0);
}

#define BARRIER() do { asm volatile("" ::: "memory"); \
                       __builtin_amdgcn_s_barrier();  \
                       asm volatile("" ::: "memory"); } while (0)

// ---------------- row sum-of-squares ---------------------------------------
__global__ void rows_sq(const float* __restrict__ in, float* __restrict__ out, int nrows) {
    int row  = blockIdx.x * 4 + (threadIdx.x >> 6);
    int lane = threadIdx.x & 63;
    if (row >= nrows) return;
    const float4* p = (const float4*)(in + (size_t)row * Dd);
    float s = 0.f;
    #pragma unroll
    for (int i = 0; i < 2; ++i) {
        float4 v = p[lane + 64 * i];
        s += v.x * v.x + v.y * v.y + v.z * v.z + v.w * v.w;
    }
    #pragma unroll
    for (int off = 32; off; off >>= 1) s += __shfl_down(s, off);
    if (lane == 0) out[row] = s;
}

// ---------------- fp32 -> bf16x3 split -------------------------------------
__global__ void conv_split(const float* __restrict__ in,
                           unsigned short* __restrict__ ph,
                           unsigned short* __restrict__ pm,
                           unsigned short* __restrict__ pl, int n4) {
    int i = blockIdx.x * 256 + threadIdx.x;
    if (i >= n4) return;
    float4 v = ((const float4*)in)[i];
    float f[4] = {v.x, v.y, v.z, v.w};
    ushort4 h, m, l;
    unsigned short hh[4], mm[4], ll[4];
    #pragma unroll
    for (int j = 0; j < 4; ++j) {
        float x = f[j];
        unsigned short a = f2bf(x);  float ra = x - bf2f(a);
        unsigned short b = f2bf(ra); float rb = ra - bf2f(b);
        unsigned short c = f2bf(rb);
        hh[j] = a; mm[j] = b; ll[j] = c;
    }
    h.x = hh[0]; h.y = hh[1]; h.z = hh[2]; h.w = hh[3];
    m.x = mm[0]; m.y = mm[1]; m.z = mm[2]; m.w = mm[3];
    l.x = ll[0]; l.y = ll[1]; l.z = ll[2]; l.w = ll[3];
    ((ushort4*)ph)[i] = h;
    ((ushort4*)pm)[i] = m;
    ((ushort4*)pl)[i] = l;
}

// ---------------- bf16x3 4-term MFMA GEMM, 256x256 tile, 4-phase -----------
// 4 terms {hh,hm,mh,mm}: A parts h,h,m,m; B parts h,m,h,m.
// K_eff = 4*512 = 2048 -> 32 K-tiles of BK=64. 8 waves (2M x 4N), 512 thr.
// LDS [2][256][64] per operand (128 KB dbuf). Stage burst (8 gloads) at ph0
// into the dead buffer (WAR-safe: dead since prev ph3 vmcnt(0)+barrier);
// single vmcnt(0) at ph3-end with ~3 phases of latency cover.
__global__ __launch_bounds__(512, 1) void gemm_split256(
    const unsigned short* __restrict__ xp,   // [3][Nn][512] bf16 planes
    const unsigned short* __restrict__ ep,   // [3][Kk][512]
    const float* __restrict__ xsq,
    const float* __restrict__ esq,
    float* __restrict__ dist,                // [Nn, Kk]
    unsigned long long* __restrict__ packed) // [Nn] argmax accumulator
{
    __shared__ unsigned short As[2][256][64];   // 64 KB
    __shared__ unsigned short Bs[2][256][64];   // 64 KB

    const int tid  = threadIdx.x;
    const int lane = tid & 63;
    const int wid  = tid >> 6;
    const int wr   = wid >> 2;   // 0..1  (M, 128 rows each)
    const int wc   = wid & 3;    // 0..3  (N, 64 cols each)

    // XCD-aware swizzle (nwg = 1024, divisible by 8 -> bijective)
    int bid = blockIdx.x;
    int wg  = (bid & 7) * 128 + (bid >> 3);
    int mb  = wg >> 3, nb = wg & 7;
    const int row0 = mb * 256, col0 = nb * 256;

    f32x4 acc[8][4] = {};
    short8 af[4], afh[4], bf[2], bfh[2];

    const int l8   = lane >> 3;          // 0..7
    const int csrc = (lane & 7) ^ l8;    // pre-swizzled source chunk

    auto stageAt = [&](const unsigned short* pl, int d, int tt) {
        int ko = (tt & 7) * 64;
        #pragma unroll
        for (int jj = 0; jj < 4; ++jj) {
            int rowbase = jj * 64 + wid * 8;
            const unsigned short* src =
                pl + (size_t)(row0 + rowbase + l8) * Dd + ko + csrc * 8;
            gload_lds16(src, &As[d][rowbase][0]);
        }
    };
    auto stageBt = [&](const unsigned short* pl, int d, int tt) {
        int ko = (tt & 7) * 64;
        #pragma unroll
        for (int jj = 0; jj < 4; ++jj) {
            int rowbase = jj * 64 + wid * 8;
            const unsigned short* src =
                pl + (size_t)(col0 + rowbase + l8) * Dd + ko + csrc * 8;
            gload_lds16(src, &Bs[d][rowbase][0]);
        }
    };

    auto readA4 = [&](int d, int msel) {
        #pragma unroll
        for (int m = 0; m < 4; ++m) {
            int r  = wr * 128 + (msel * 4 + m) * 16 + (lane & 15);
            int c  = ((lane >> 4))     ^ (r & 7);
            int c2 = ((lane >> 4) + 4) ^ (r & 7);
            af[m]  = *(const short8*)&As[d][r][c * 8];
            afh[m] = *(const short8*)&As[d][r][c2 * 8];
        }
    };
    auto readB2 = [&](int d, int nsel) {
        #pragma unroll
        for (int n = 0; n < 2; ++n) {
            int r  = wc * 64 + (nsel * 2 + n) * 16 + (lane & 15);
            int c  = ((lane >> 4))     ^ (r & 7);
            int c2 = ((lane >> 4) + 4) ^ (r & 7);
            bf[n]  = *(const short8*)&Bs[d][r][c * 8];
            bfh[n] = *(const short8*)&Bs[d][r][c2 * 8];
        }
    };

    auto mfmaQ = [&](int msel, int nsel) {
        __builtin_amdgcn_s_setprio(1);
        #pragma unroll
        for (int m = 0; m < 4; ++m)
            #pragma unroll
            for (int n = 0; n < 2; ++n) {
                int am = msel * 4 + m, bn = nsel * 2 + n;
                acc[am][bn] = __builtin_amdgcn_mfma_f32_16x16x32_bf16(af[m], bf[n], acc[am][bn], 0, 0, 0);
            }
        #pragma unroll
        for (int m = 0; m < 4; ++m)
            #pragma unroll
            for (int n = 0; n < 2; ++n) {
                int am = msel * 4 + m, bn = nsel * 2 + n;
                acc[am][bn] = __builtin_amdgcn_mfma_f32_16x16x32_bf16(afh[m], bfh[n], acc[am][bn], 0, 0, 0);
            }
        __builtin_amdgcn_s_setprio(0);
    };

    // prologue: stage tile 0 into slot 0
    stageAt(xp, 0, 0);
    stageBt(ep, 0, 0);
    asm volatile("s_waitcnt vmcnt(0)" ::: "memory");
    BARRIER();

    for (int t = 0; t < 32; ++t) {
        const int cur = t & 1, nxt = cur ^ 1;
        const bool st = (t < 31);
        // plane pointers for tile t+1 (overrun t=32 -> pn=4 -> A:h, B:h; valid)
        int pn = (t + 1) >> 3;   // A: h,h,m,m   B: h,m,h,m
        const unsigned short* Apn = xp + (size_t)((pn == 2 || pn == 3) ? 1 : 0) * ((size_t)Nn * Dd);
        const unsigned short* Bpn = ep + (size_t)((pn == 1 || pn == 3) ? 1 : 0) * ((size_t)Kk * Dd);

        // ---- ph0 ----
        readA4(cur, 0); readB2(cur, 0);
        if (st) { stageAt(Apn, nxt, t + 1); stageBt(Bpn, nxt, t + 1); }
        mfmaQ(0, 0);
        BARRIER();
        // ---- ph1 ----
        readB2(cur, 1);
        mfmaQ(0, 1);
        BARRIER();
        // ---- ph2 ----
        readA4(cur, 1);
        mfmaQ(1, 1);
        BARRIER();
        // ---- ph3 ----
        readB2(cur, 0);
        mfmaQ(1, 0);
        asm volatile("s_waitcnt vmcnt(0)" ::: "memory");
        BARRIER();
    }

    // epilogue: dist = 2*dot - xsq - esq ; fused per-row argmax
    const int jrow = (lane >> 4) * 4;
    const int ncol = lane & 15;
    #pragma unroll
    for (int m = 0; m < 8; ++m) {
        int rbase = row0 + wr * 128 + m * 16 + jrow;
        #pragma unroll
        for (int j = 0; j < 4; ++j) {
            int row = rbase + j;
            float xs = xsq[row];
            float best = -3.4e38f; int bi = 0;
            #pragma unroll
            for (int n = 0; n < 4; ++n) {
                int col = col0 + wc * 64 + n * 16 + ncol;
                float v = 2.f * acc[m][n][j] - xs - esq[col];
                dist[(size_t)row * Kk + col] = v;
                if (v > best) { best = v; bi = col; }
            }
            unsigned u = __float_as_uint(best);
            u = (u & 0x80000000u) ? ~u : (u | 0x80000000u);
            unsigned long long pk = ((unsigned long long)u << 32) | (unsigned)(~bi);
            #pragma unroll
            for (int off = 1; off < 16; off <<= 1) {
                unsigned long long o = __shfl_xor(pk, off);
                if (o > pk) pk = o;
            }
            if (ncol == 0) atomicMax(&packed[row], pk);
        }
    }
}

__global__ void unpack_argmax(const unsigned long long* __restrict__ packed,
                              float* __restrict__ ind_f, int* __restrict__ ind_i) {
    int i = blockIdx.x * 256 + threadIdx.x;
    unsigned long long p = packed[i];
    int k = (int)(~(unsigned)(p & 0xFFFFFFFFull));
    ind_f[i] = (float)k;
    ind_i[i] = k;
}

// ---------------- OLD fp32 GEMM (fallback when ws too small) ---------------
#define BM 64
#define BN 64
#define BK 32
__global__ __launch_bounds__(256) void gemm_dist(
    const float* __restrict__ A, const float* __restrict__ Bm,
    const float* __restrict__ xsq, const float* __restrict__ esq,
    float* __restrict__ dist)
{
    __shared__ float Asl[BK][BM + 4];
    __shared__ float Bsl[BK][BN + 4];
    int tid = threadIdx.x;
    int row0 = blockIdx.x * BM, col0 = blockIdx.y * BN;
    int tx = tid & 15, ty = tid >> 4;
    float acc[4][4] = {};
    int lr = tid >> 3, lc = (tid & 7) * 4;
    for (int d0 = 0; d0 < Dd; d0 += BK) {
        float4 a0 = *(const float4*)(A  + (size_t)(row0 + lr)      * Dd + d0 + lc);
        float4 a1 = *(const float4*)(A  + (size_t)(row0 + lr + 32) * Dd + d0 + lc);
        float4 b0 = *(const float4*)(Bm + (size_t)(col0 + lr)      * Dd + d0 + lc);
        float4 b1 = *(const float4*)(Bm + (size_t)(col0 + lr + 32) * Dd + d0 + lc);
        __syncthreads();
        Asl[lc + 0][lr] = a0.x; Asl[lc + 1][lr] = a0.y; Asl[lc + 2][lr] = a0.z; Asl[lc + 3][lr] = a0.w;
        Asl[lc + 0][lr + 32] = a1.x; Asl[lc + 1][lr + 32] = a1.y; Asl[lc + 2][lr + 32] = a1.z; Asl[lc + 3][lr + 32] = a1.w;
        Bsl[lc + 0][lr] = b0.x; Bsl[lc + 1][lr] = b0.y; Bsl[lc + 2][lr] = b0.z; Bsl[lc + 3][lr] = b0.w;
        Bsl[lc + 0][lr + 32] = b1.x; Bsl[lc + 1][lr + 32] = b1.y; Bsl[lc + 2][lr + 32] = b1.z; Bsl[lc + 3][lr + 32] = b1.w;
        __syncthreads();
        #pragma unroll
        for (int kd = 0; kd < BK; ++kd) {
            float4 av = *(const float4*)&Asl[kd][ty * 4];
            float4 bv = *(const float4*)&Bsl[kd][tx * 4];
            float a[4] = {av.x, av.y, av.z, av.w};
            float b[4] = {bv.x, bv.y, bv.z, bv.w};
            #pragma unroll
            for (int i = 0; i < 4; ++i)
                #pragma unroll
                for (int j = 0; j < 4; ++j)
                    acc[i][j] = fmaf(a[i], b[j], acc[i][j]);
        }
    }
    #pragma unroll
    for (int i = 0; i < 4; ++i) {
        int row = row0 + ty * 4 + i;
        float xs = xsq[row];
        float4 o;
        int col = col0 + tx * 4;
        o.x = 2.f * acc[i][0] - xs - esq[col + 0];
        o.y = 2.f * acc[i][1] - xs - esq[col + 1];
        o.z = 2.f * acc[i][2] - xs - esq[col + 2];
        o.w = 2.f * acc[i][3] - xs - esq[col + 3];
        *(float4*)(dist + (size_t)row * Kk + col) = o;
    }
}

__global__ void argmax_k(const float* __restrict__ dist,
                         float* __restrict__ ind_f, int* __restrict__ ind_i) {
    int row  = blockIdx.x * 4 + (threadIdx.x >> 6);
    int lane = threadIdx.x & 63;
    const float4* p = (const float4*)(dist + (size_t)row * Kk);
    float best = -3.4e38f;
    int bidx = 0;
    #pragma unroll
    for (int it = 0; it < Kk / 4 / 64; ++it) {
        int i = lane + it * 64;
        float4 v = p[i];
        int base = i * 4;
        if (v.x > best) { best = v.x; bidx = base + 0; }
        if (v.y > best) { best = v.y; bidx = base + 1; }
        if (v.z > best) { best = v.z; bidx = base + 2; }
        if (v.w > best) { best = v.w; bidx = base + 3; }
    }
    #pragma unroll
    for (int off = 32; off; off >>= 1) {
        float ov = __shfl_down(best, off);
        int   oi = __shfl_down(bidx, off);
        if (ov > best || (ov == best && oi < bidx)) { best = ov; bidx = oi; }
    }
    if (lane == 0) { ind_f[row] = (float)bidx; ind_i[row] = bidx; }
}

// ---------------- quantize gather + segment-sum scatter --------------------
__global__ void gather_scatter(const float* __restrict__ x,
                               const float* __restrict__ embed,
                               const int* __restrict__ ind,
                               float* __restrict__ quant,
                               float* __restrict__ esum,
                               int* __restrict__ bins) {
    int n = blockIdx.x;
    int k = ind[n];
    int t = threadIdx.x;
    size_t xb = (size_t)n * Dd;
    size_t eb = (size_t)k * Dd;
    float v0 = x[xb + t];
    float v1 = x[xb + t + 256];
    quant[xb + t]       = embed[eb + t];
    quant[xb + t + 256] = embed[eb + t + 256];
    atomicAdd(&esum[eb + t],       v0);
    atomicAdd(&esum[eb + t + 256], v1);
    if (t == 0) atomicAdd(&bins[k], 1);
}

// ---------------- EMA cluster size + laplace total -------------------------
__global__ void finalize1(const float* __restrict__ cs, const int* __restrict__ bins,
                          float* __restrict__ ncs, float* __restrict__ total_ws) {
    __shared__ float red[16];
    int t = threadIdx.x;
    float s = 0.f;
    for (int k = t; k < Kk; k += 1024) {
        float v = cs[k] * DECAY + OMD * (float)bins[k];
        ncs[k] = v;
        s += v;
    }
    #pragma unroll
    for (int off = 32; off; off >>= 1) s += __shfl_down(s, off);
    if ((t & 63) == 0) red[t >> 6] = s;
    __syncthreads();
    if (t == 0) {
        float tot = 0.f;
        #pragma unroll
        for (int i = 0; i < 16; ++i) tot += red[i];
        total_ws[0] = tot;
    }
}

// ---------------- EMA embed_avg + smoothed divide ---------------------------
__global__ void finalize2(const float* __restrict__ ea, const float* __restrict__ esum,
                          const float* __restrict__ ncs, const float* __restrict__ total_ws,
                          float* __restrict__ nea, float* __restrict__ ne) {
    int idx = blockIdx.x * 256 + threadIdx.x;
    float total = total_ws[0];
    int k = idx >> 7;
    float sm = (ncs[k] + EPS) / (total + Kk * EPS) * total;
    float inv = 1.f / sm;
    float4 a = ((const float4*)ea)[idx];
    float4 s = ((const float4*)esum)[idx];
    float4 r;
    r.x = a.x * DECAY + OMD * s.x;
    r.y = a.y * DECAY + OMD * s.y;
    r.z = a.z * DECAY + OMD * s.z;
    r.w = a.w * DECAY + OMD * s.w;
    ((float4*)nea)[idx] = r;
    float4 e;
    e.x = r.x * inv; e.y = r.y * inv; e.z = r.z * inv; e.w = r.w * inv;
    ((float4*)ne)[idx] = e;
}

extern "C" void kernel_launch(void* const* d_in, const int* in_sizes, int n_in,
                              void* d_out, int out_size, void* d_ws, size_t ws_size,
                              hipStream_t stream) {
    const float* x     = (const float*)d_in[0];
    const float* embed = (const float*)d_in[1];
    const float* cs    = (const float*)d_in[2];
    const float* ea    = (const float*)d_in[3];

    float* out     = (float*)d_out;
    float* o_quant = out;
    float* o_ind   = o_quant + (size_t)Nn * Dd;
    float* o_dist  = o_ind + Nn;
    float* o_ncs   = o_dist + (size_t)Nn * Kk;
    float* o_nea   = o_ncs + Kk;
    float* o_ne    = o_nea + (size_t)Kk * Dd;

    // ---- ws layout ----
    size_t xp_elems = (size_t)3 * Nn * Dd;       // bf16
    size_t ep_elems = (size_t)3 * Kk * Dd;
    char* w = (char*)d_ws;
    unsigned short* xp = (unsigned short*)w;                 w += xp_elems * 2;
    unsigned short* epp = (unsigned short*)w;                w += ep_elems * 2;
    float* xsq   = (float*)w;                                w += (size_t)Nn * 4;
    float* esq   = (float*)w;                                w += (size_t)Kk * 4;
    int*   ind_i = (int*)w;                                  w += (size_t)Nn * 4;
    int*   bins  = (int*)w;                                  w += (size_t)Kk * 4;
    float* esum  = (float*)w;                                w += (size_t)Kk * Dd * 4;
    unsigned long long* packed = (unsigned long long*)w;     w += (size_t)Nn * 8;
    float* total = (float*)w;                                w += 256;
    size_t need = (size_t)(w - (char*)d_ws);

    if (ws_size >= need) {
        hipMemsetAsync(bins, 0, (size_t)Kk * 4 + (size_t)Kk * Dd * 4 + (size_t)Nn * 8, stream);

        rows_sq<<<Nn / 4, 256, 0, stream>>>(x, xsq, Nn);
        rows_sq<<<Kk / 4, 256, 0, stream>>>(embed, esq, Kk);

        conv_split<<<(Nn * Dd / 4 + 255) / 256, 256, 0, stream>>>(
            x, xp, xp + (size_t)Nn * Dd, xp + (size_t)2 * Nn * Dd, Nn * Dd / 4);
        conv_split<<<(Kk * Dd / 4 + 255) / 256, 256, 0, stream>>>(
            embed, epp, epp + (size_t)Kk * Dd, epp + (size_t)2 * Kk * Dd, Kk * Dd / 4);

        gemm_split256<<<(Nn / 256) * (Kk / 256), 512, 0, stream>>>(
            xp, epp, xsq, esq, o_dist, packed);

        unpack_argmax<<<Nn / 256, 256, 0, stream>>>(packed, o_ind, ind_i);
    } else {
        float* fxsq  = (float*)d_ws;
        float* fesq  = fxsq + Nn;
        int*   find  = (int*)(fesq + Kk);
        int*   fbins = find + Nn;
        float* fesum = (float*)(fbins + Kk);
        float* ftot  = fesum + (size_t)Kk * Dd;
        xsq = fxsq; esq = fesq; ind_i = find; bins = fbins; esum = fesum; total = ftot;

        hipMemsetAsync(bins, 0, (size_t)(Kk + Kk * Dd) * sizeof(float), stream);
        rows_sq<<<Nn / 4, 256, 0, stream>>>(x, xsq, Nn);
        rows_sq<<<Kk / 4, 256, 0, stream>>>(embed, esq, Kk);
        dim3 g(Nn / BM, Kk / BN);
        gemm_dist<<<g, 256, 0, stream>>>(x, embed, xsq, esq, o_dist);
        argmax_k<<<Nn / 4, 256, 0, stream>>>(o_dist, o_ind, ind_i);
    }

    gather_scatter<<<Nn, 256, 0, stream>>>(x, embed, ind_i, o_quant, esum, bins);
    finalize1<<<1, 1024, 0, stream>>>(cs, bins, o_ncs, total);
    finalize2<<<(Kk * Dd / 4) / 256, 256, 0, stream>>>(ea, esum, o_ncs, total, o_nea, o_ne);
}

// Round 10
// 440.804 us; speedup vs baseline: 1.3732x; 1.0360x over previous
//
#include <hip/hip_runtime.h>

#define DECAY 0.99f
#define OMD   0.01f
#define EPS   1e-5f

constexpr int Bb = 16, Ss = 2048, Dd = 512, Kk = 2048;
constexpr int Nn = Bb * Ss;  // 32768

typedef __attribute__((ext_vector_type(8))) short short8;
typedef __attribute__((ext_vector_type(4))) float f32x4;

__device__ __forceinline__ unsigned short f2bf(float x) {
    unsigned u = __float_as_uint(x);
    unsigned r = (u + 0x7FFFu + ((u >> 16) & 1u)) >> 16;   // RN-even
    return (unsigned short)r;
}
__device__ __forceinline__ float bf2f(unsigned short u) {
    return __uint_as_float((unsigned)u << 16);
}

__device__ __forceinline__ void gload_lds16(const void* g, void* l) {
    __builtin_amdgcn_global_load_lds(
        (const __attribute__((address_space(1))) void*)g,
        (__attribute__((address_space(3))) void*)l, 16, 0, 0);
}

#define BARRIER() do { asm volatile("" ::: "memory"); \
                       __builtin_amdgcn_s_barrier();  \
                       asm volatile("" ::: "memory"); } while (0)

// ---------------- row sum-of-squares ---------------------------------------
__global__ void rows_sq(const float* __restrict__ in, float* __restrict__ out, int nrows) {
    int row  = blockIdx.x * 4 + (threadIdx.x >> 6);
    int lane = threadIdx.x & 63;
    if (row >= nrows) return;
    const float4* p = (const float4*)(in + (size_t)row * Dd);
    float s = 0.f;
    #pragma unroll
    for (int i = 0; i < 2; ++i) {
        float4 v = p[lane + 64 * i];
        s += v.x * v.x + v.y * v.y + v.z * v.z + v.w * v.w;
    }
    #pragma unroll
    for (int off = 32; off; off >>= 1) s += __shfl_down(s, off);
    if (lane == 0) out[row] = s;
}

// ---------------- fp32 -> bf16x2 split (h,m only — 4-term path) ------------
__global__ void conv_split2(const float* __restrict__ in,
                            unsigned short* __restrict__ ph,
                            unsigned short* __restrict__ pm, int n4) {
    int i = blockIdx.x * 256 + threadIdx.x;
    if (i >= n4) return;
    float4 v = ((const float4*)in)[i];
    float f[4] = {v.x, v.y, v.z, v.w};
    ushort4 h, m;
    unsigned short hh[4], mm[4];
    #pragma unroll
    for (int j = 0; j < 4; ++j) {
        float x = f[j];
        unsigned short a = f2bf(x);  float ra = x - bf2f(a);
        unsigned short b = f2bf(ra);
        hh[j] = a; mm[j] = b;
    }
    h.x = hh[0]; h.y = hh[1]; h.z = hh[2]; h.w = hh[3];
    m.x = mm[0]; m.y = mm[1]; m.z = mm[2]; m.w = mm[3];
    ((ushort4*)ph)[i] = h;
    ((ushort4*)pm)[i] = m;
}

// ---------------- bf16x2 4-term MFMA GEMM, 256x256 tile, 1 barrier/K-tile --
// 4 terms {hh,hm,mh,mm}: A parts h,h,m,m; B parts h,m,h,m.
// K_eff = 2048 -> 32 K-tiles of BK=64. 8 waves (2M x 4N), 512 thr.
// NO intra-tile barriers: stages write only the dead buffer, reads only the
// live one, so a single end-of-tile vmcnt(0)+barrier gives exactly one
// barrier between any buffer's last read and next overwrite. Waves slip
// freely within a K-tile -> cross-wave overlap of ds_read and MFMA pipes.
__global__ __launch_bounds__(512, 1) void gemm_split256(
    const unsigned short* __restrict__ xp,   // [3][Nn][512] bf16 planes (h,m,-)
    const unsigned short* __restrict__ ep,   // [3][Kk][512]
    const float* __restrict__ xsq,
    const float* __restrict__ esq,
    float* __restrict__ dist,                // [Nn, Kk]
    unsigned long long* __restrict__ packed) // [Nn] argmax accumulator
{
    __shared__ unsigned short As[2][256][64];   // 64 KB
    __shared__ unsigned short Bs[2][256][64];   // 64 KB

    const int tid  = threadIdx.x;
    const int lane = tid & 63;
    const int wid  = tid >> 6;
    const int wr   = wid >> 2;   // 0..1  (M, 128 rows each)
    const int wc   = wid & 3;    // 0..3  (N, 64 cols each)

    // XCD-aware swizzle (nwg = 1024, divisible by 8 -> bijective)
    int bid = blockIdx.x;
    int wg  = (bid & 7) * 128 + (bid >> 3);
    int mb  = wg >> 3, nb = wg & 7;
    const int row0 = mb * 256, col0 = nb * 256;

    f32x4 acc[8][4] = {};
    short8 af[4], afh[4], bl[2], blh[2], bh[2], bhh[2];

    const int l8   = lane >> 3;          // 0..7
    const int csrc = (lane & 7) ^ l8;    // pre-swizzled source chunk

    auto stageAt = [&](const unsigned short* pl, int d, int tt) {
        int ko = (tt & 7) * 64;
        #pragma unroll
        for (int jj = 0; jj < 4; ++jj) {
            int rowbase = jj * 64 + wid * 8;
            const unsigned short* src =
                pl + (size_t)(row0 + rowbase + l8) * Dd + ko + csrc * 8;
            gload_lds16(src, &As[d][rowbase][0]);
        }
    };
    auto stageBt = [&](const unsigned short* pl, int d, int tt) {
        int ko = (tt & 7) * 64;
        #pragma unroll
        for (int jj = 0; jj < 4; ++jj) {
            int rowbase = jj * 64 + wid * 8;
            const unsigned short* src =
                pl + (size_t)(col0 + rowbase + l8) * Dd + ko + csrc * 8;
            gload_lds16(src, &Bs[d][rowbase][0]);
        }
    };

    auto readA4 = [&](int d, int msel) {
        #pragma unroll
        for (int m = 0; m < 4; ++m) {
            int r  = wr * 128 + (msel * 4 + m) * 16 + (lane & 15);
            int c  = ((lane >> 4))     ^ (r & 7);
            int c2 = ((lane >> 4) + 4) ^ (r & 7);
            af[m]  = *(const short8*)&As[d][r][c * 8];
            afh[m] = *(const short8*)&As[d][r][c2 * 8];
        }
    };
    auto readBlo = [&](int d) {
        #pragma unroll
        for (int n = 0; n < 2; ++n) {
            int r  = wc * 64 + n * 16 + (lane & 15);
            int c  = ((lane >> 4))     ^ (r & 7);
            int c2 = ((lane >> 4) + 4) ^ (r & 7);
            bl[n]  = *(const short8*)&Bs[d][r][c * 8];
            blh[n] = *(const short8*)&Bs[d][r][c2 * 8];
        }
    };
    auto readBhi = [&](int d) {
        #pragma unroll
        for (int n = 0; n < 2; ++n) {
            int r  = wc * 64 + (2 + n) * 16 + (lane & 15);
            int c  = ((lane >> 4))     ^ (r & 7);
            int c2 = ((lane >> 4) + 4) ^ (r & 7);
            bh[n]  = *(const short8*)&Bs[d][r][c * 8];
            bhh[n] = *(const short8*)&Bs[d][r][c2 * 8];
        }
    };

    auto mfmaQ = [&](int msel, int nsel, const short8* b0, const short8* b1) {
        #pragma unroll
        for (int m = 0; m < 4; ++m)
            #pragma unroll
            for (int n = 0; n < 2; ++n) {
                int am = msel * 4 + m, bn = nsel * 2 + n;
                acc[am][bn] = __builtin_amdgcn_mfma_f32_16x16x32_bf16(af[m], b0[n], acc[am][bn], 0, 0, 0);
            }
        #pragma unroll
        for (int m = 0; m < 4; ++m)
            #pragma unroll
            for (int n = 0; n < 2; ++n) {
                int am = msel * 4 + m, bn = nsel * 2 + n;
                acc[am][bn] = __builtin_amdgcn_mfma_f32_16x16x32_bf16(afh[m], b1[n], acc[am][bn], 0, 0, 0);
            }
    };

    // prologue: stage tile 0 into slot 0
    stageAt(xp, 0, 0);
    stageBt(ep, 0, 0);
    asm volatile("s_waitcnt vmcnt(0)" ::: "memory");
    BARRIER();

    for (int t = 0; t < 32; ++t) {
        const int cur = t & 1, nxt = cur ^ 1;
        const bool st = (t < 31);
        // plane pointers for tile t+1 (overrun t=32 -> pn=4 -> A:h, B:h; valid)
        int pn = (t + 1) >> 3;   // A: h,h,m,m   B: h,m,h,m
        const unsigned short* Apn = xp + (size_t)((pn == 2 || pn == 3) ? 1 : 0) * ((size_t)Nn * Dd);
        const unsigned short* Bpn = ep + (size_t)((pn == 1 || pn == 3) ? 1 : 0) * ((size_t)Kk * Dd);

        readA4(cur, 0); readBlo(cur); readBhi(cur);
        if (st) { stageAt(Apn, nxt, t + 1); stageBt(Bpn, nxt, t + 1); }
        mfmaQ(0, 0, bl, blh);
        mfmaQ(0, 1, bh, bhh);
        readA4(cur, 1);
        mfmaQ(1, 1, bh, bhh);
        mfmaQ(1, 0, bl, blh);
        asm volatile("s_waitcnt vmcnt(0)" ::: "memory");
        BARRIER();
    }

    // epilogue: dist = 2*dot - xsq - esq ; fused per-row argmax
    const int jrow = (lane >> 4) * 4;
    const int ncol = lane & 15;
    #pragma unroll
    for (int m = 0; m < 8; ++m) {
        int rbase = row0 + wr * 128 + m * 16 + jrow;
        #pragma unroll
        for (int j = 0; j < 4; ++j) {
            int row = rbase + j;
            float xs = xsq[row];
            float best = -3.4e38f; int bi = 0;
            #pragma unroll
            for (int n = 0; n < 4; ++n) {
                int col = col0 + wc * 64 + n * 16 + ncol;
                float v = 2.f * acc[m][n][j] - xs - esq[col];
                dist[(size_t)row * Kk + col] = v;
                if (v > best) { best = v; bi = col; }
            }
            unsigned u = __float_as_uint(best);
            u = (u & 0x80000000u) ? ~u : (u | 0x80000000u);
            unsigned long long pk = ((unsigned long long)u << 32) | (unsigned)(~bi);
            #pragma unroll
            for (int off = 1; off < 16; off <<= 1) {
                unsigned long long o = __shfl_xor(pk, off);
                if (o > pk) pk = o;
            }
            if (ncol == 0) atomicMax(&packed[row], pk);
        }
    }
}

__global__ void unpack_argmax(const unsigned long long* __restrict__ packed,
                              float* __restrict__ ind_f, int* __restrict__ ind_i) {
    int i = blockIdx.x * 256 + threadIdx.x;
    unsigned long long p = packed[i];
    int k = (int)(~(unsigned)(p & 0xFFFFFFFFull));
    ind_f[i] = (float)k;
    ind_i[i] = k;
}

// ---------------- OLD fp32 GEMM (fallback when ws too small) ---------------
#define BM 64
#define BN 64
#define BK 32
__global__ __launch_bounds__(256) void gemm_dist(
    const float* __restrict__ A, const float* __restrict__ Bm,
    const float* __restrict__ xsq, const float* __restrict__ esq,
    float* __restrict__ dist)
{
    __shared__ float Asl[BK][BM + 4];
    __shared__ float Bsl[BK][BN + 4];
    int tid = threadIdx.x;
    int row0 = blockIdx.x * BM, col0 = blockIdx.y * BN;
    int tx = tid & 15, ty = tid >> 4;
    float acc[4][4] = {};
    int lr = tid >> 3, lc = (tid & 7) * 4;
    for (int d0 = 0; d0 < Dd; d0 += BK) {
        float4 a0 = *(const float4*)(A  + (size_t)(row0 + lr)      * Dd + d0 + lc);
        float4 a1 = *(const float4*)(A  + (size_t)(row0 + lr + 32) * Dd + d0 + lc);
        float4 b0 = *(const float4*)(Bm + (size_t)(col0 + lr)      * Dd + d0 + lc);
        float4 b1 = *(const float4*)(Bm + (size_t)(col0 + lr + 32) * Dd + d0 + lc);
        __syncthreads();
        Asl[lc + 0][lr] = a0.x; Asl[lc + 1][lr] = a0.y; Asl[lc + 2][lr] = a0.z; Asl[lc + 3][lr] = a0.w;
        Asl[lc + 0][lr + 32] = a1.x; Asl[lc + 1][lr + 32] = a1.y; Asl[lc + 2][lr + 32] = a1.z; Asl[lc + 3][lr + 32] = a1.w;
        Bsl[lc + 0][lr] = b0.x; Bsl[lc + 1][lr] = b0.y; Bsl[lc + 2][lr] = b0.z; Bsl[lc + 3][lr] = b0.w;
        Bsl[lc + 0][lr + 32] = b1.x; Bsl[lc + 1][lr + 32] = b1.y; Bsl[lc + 2][lr + 32] = b1.z; Bsl[lc + 3][lr + 32] = b1.w;
        __syncthreads();
        #pragma unroll
        for (int kd = 0; kd < BK; ++kd) {
            float4 av = *(const float4*)&Asl[kd][ty * 4];
            float4 bv = *(const float4*)&Bsl[kd][tx * 4];
            float a[4] = {av.x, av.y, av.z, av.w};
            float b[4] = {bv.x, bv.y, bv.z, bv.w};
            #pragma unroll
            for (int i = 0; i < 4; ++i)
                #pragma unroll
                for (int j = 0; j < 4; ++j)
                    acc[i][j] = fmaf(a[i], b[j], acc[i][j]);
        }
    }
    #pragma unroll
    for (int i = 0; i < 4; ++i) {
        int row = row0 + ty * 4 + i;
        float xs = xsq[row];
        float4 o;
        int col = col0 + tx * 4;
        o.x = 2.f * acc[i][0] - xs - esq[col + 0];
        o.y = 2.f * acc[i][1] - xs - esq[col + 1];
        o.z = 2.f * acc[i][2] - xs - esq[col + 2];
        o.w = 2.f * acc[i][3] - xs - esq[col + 3];
        *(float4*)(dist + (size_t)row * Kk + col) = o;
    }
}

__global__ void argmax_k(const float* __restrict__ dist,
                         float* __restrict__ ind_f, int* __restrict__ ind_i) {
    int row  = blockIdx.x * 4 + (threadIdx.x >> 6);
    int lane = threadIdx.x & 63;
    const float4* p = (const float4*)(dist + (size_t)row * Kk);
    float best = -3.4e38f;
    int bidx = 0;
    #pragma unroll
    for (int it = 0; it < Kk / 4 / 64; ++it) {
        int i = lane + it * 64;
        float4 v = p[i];
        int base = i * 4;
        if (v.x > best) { best = v.x; bidx = base + 0; }
        if (v.y > best) { best = v.y; bidx = base + 1; }
        if (v.z > best) { best = v.z; bidx = base + 2; }
        if (v.w > best) { best = v.w; bidx = base + 3; }
    }
    #pragma unroll
    for (int off = 32; off; off >>= 1) {
        float ov = __shfl_down(best, off);
        int   oi = __shfl_down(bidx, off);
        if (ov > best || (ov == best && oi < bidx)) { best = ov; bidx = oi; }
    }
    if (lane == 0) { ind_f[row] = (float)bidx; ind_i[row] = bidx; }
}

// ---------------- quantize gather + segment-sum scatter --------------------
__global__ void gather_scatter(const float* __restrict__ x,
                               const float* __restrict__ embed,
                               const int* __restrict__ ind,
                               float* __restrict__ quant,
                               float* __restrict__ esum,
                               int* __restrict__ bins) {
    int n = blockIdx.x;
    int k = ind[n];
    int t = threadIdx.x;
    size_t xb = (size_t)n * Dd;
    size_t eb = (size_t)k * Dd;
    float v0 = x[xb + t];
    float v1 = x[xb + t + 256];
    quant[xb + t]       = embed[eb + t];
    quant[xb + t + 256] = embed[eb + t + 256];
    atomicAdd(&esum[eb + t],       v0);
    atomicAdd(&esum[eb + t + 256], v1);
    if (t == 0) atomicAdd(&bins[k], 1);
}

// ---------------- EMA cluster size + laplace total -------------------------
__global__ void finalize1(const float* __restrict__ cs, const int* __restrict__ bins,
                          float* __restrict__ ncs, float* __restrict__ total_ws) {
    __shared__ float red[16];
    int t = threadIdx.x;
    float s = 0.f;
    for (int k = t; k < Kk; k += 1024) {
        float v = cs[k] * DECAY + OMD * (float)bins[k];
        ncs[k] = v;
        s += v;
    }
    #pragma unroll
    for (int off = 32; off; off >>= 1) s += __shfl_down(s, off);
    if ((t & 63) == 0) red[t >> 6] = s;
    __syncthreads();
    if (t == 0) {
        float tot = 0.f;
        #pragma unroll
        for (int i = 0; i < 16; ++i) tot += red[i];
        total_ws[0] = tot;
    }
}

// ---------------- EMA embed_avg + smoothed divide ---------------------------
__global__ void finalize2(const float* __restrict__ ea, const float* __restrict__ esum,
                          const float* __restrict__ ncs, const float* __restrict__ total_ws,
                          float* __restrict__ nea, float* __restrict__ ne) {
    int idx = blockIdx.x * 256 + threadIdx.x;
    float total = total_ws[0];
    int k = idx >> 7;
    float sm = (ncs[k] + EPS) / (total + Kk * EPS) * total;
    float inv = 1.f / sm;
    float4 a = ((const float4*)ea)[idx];
    float4 s = ((const float4*)esum)[idx];
    float4 r;
    r.x = a.x * DECAY + OMD * s.x;
    r.y = a.y * DECAY + OMD * s.y;
    r.z = a.z * DECAY + OMD * s.z;
    r.w = a.w * DECAY + OMD * s.w;
    ((float4*)nea)[idx] = r;
    float4 e;
    e.x = r.x * inv; e.y = r.y * inv; e.z = r.z * inv; e.w = r.w * inv;
    ((float4*)ne)[idx] = e;
}

extern "C" void kernel_launch(void* const* d_in, const int* in_sizes, int n_in,
                              void* d_out, int out_size, void* d_ws, size_t ws_size,
                              hipStream_t stream) {
    const float* x     = (const float*)d_in[0];
    const float* embed = (const float*)d_in[1];
    const float* cs    = (const float*)d_in[2];
    const float* ea    = (const float*)d_in[3];

    float* out     = (float*)d_out;
    float* o_quant = out;
    float* o_ind   = o_quant + (size_t)Nn * Dd;
    float* o_dist  = o_ind + Nn;
    float* o_ncs   = o_dist + (size_t)Nn * Kk;
    float* o_nea   = o_ncs + Kk;
    float* o_ne    = o_nea + (size_t)Kk * Dd;

    // ---- ws layout (3-plane strides kept; plane 2 unused in 4-term path) ----
    size_t xp_elems = (size_t)3 * Nn * Dd;       // bf16
    size_t ep_elems = (size_t)3 * Kk * Dd;
    char* w = (char*)d_ws;
    unsigned short* xp = (unsigned short*)w;                 w += xp_elems * 2;
    unsigned short* epp = (unsigned short*)w;                w += ep_elems * 2;
    float* xsq   = (float*)w;                                w += (size_t)Nn * 4;
    float* esq   = (float*)w;                                w += (size_t)Kk * 4;
    int*   ind_i = (int*)w;                                  w += (size_t)Nn * 4;
    int*   bins  = (int*)w;                                  w += (size_t)Kk * 4;
    float* esum  = (float*)w;                                w += (size_t)Kk * Dd * 4;
    unsigned long long* packed = (unsigned long long*)w;     w += (size_t)Nn * 8;
    float* total = (float*)w;                                w += 256;
    size_t need = (size_t)(w - (char*)d_ws);

    if (ws_size >= need) {
        hipMemsetAsync(bins, 0, (size_t)Kk * 4 + (size_t)Kk * Dd * 4 + (size_t)Nn * 8, stream);

        rows_sq<<<Nn / 4, 256, 0, stream>>>(x, xsq, Nn);
        rows_sq<<<Kk / 4, 256, 0, stream>>>(embed, esq, Kk);

        conv_split2<<<(Nn * Dd / 4 + 255) / 256, 256, 0, stream>>>(
            x, xp, xp + (size_t)Nn * Dd, Nn * Dd / 4);
        conv_split2<<<(Kk * Dd / 4 + 255) / 256, 256, 0, stream>>>(
            embed, epp, epp + (size_t)Kk * Dd, Kk * Dd / 4);

        gemm_split256<<<(Nn / 256) * (Kk / 256), 512, 0, stream>>>(
            xp, epp, xsq, esq, o_dist, packed);

        unpack_argmax<<<Nn / 256, 256, 0, stream>>>(packed, o_ind, ind_i);
    } else {
        float* fxsq  = (float*)d_ws;
        float* fesq  = fxsq + Nn;
        int*   find  = (int*)(fesq + Kk);
        int*   fbins = find + Nn;
        float* fesum = (float*)(fbins + Kk);
        float* ftot  = fesum + (size_t)Kk * Dd;
        xsq = fxsq; esq = fesq; ind_i = find; bins = fbins; esum = fesum; total = ftot;

        hipMemsetAsync(bins, 0, (size_t)(Kk + Kk * Dd) * sizeof(float), stream);
        rows_sq<<<Nn / 4, 256, 0, stream>>>(x, xsq, Nn);
        rows_sq<<<Kk / 4, 256, 0, stream>>>(embed, esq, Kk);
        dim3 g(Nn / BM, Kk / BN);
        gemm_dist<<<g, 256, 0, stream>>>(x, embed, xsq, esq, o_dist);
        argmax_k<<<Nn / 4, 256, 0, stream>>>(o_dist, o_ind, ind_i);
    }

    gather_scatter<<<Nn, 256, 0, stream>>>(x, embed, ind_i, o_quant, esum, bins);
    finalize1<<<1, 1024, 0, stream>>>(cs, bins, o_ncs, total);
    finalize2<<<(Kk * Dd / 4) / 256, 256, 0, stream>>>(ea, esum, o_ncs, total, o_nea, o_ne);
}

// Round 11
// 438.788 us; speedup vs baseline: 1.3795x; 1.0046x over previous
//
#include <hip/hip_runtime.h>

#define DECAY 0.99f
#define OMD   0.01f
#define EPS   1e-5f

constexpr int Bb = 16, Ss = 2048, Dd = 512, Kk = 2048;
constexpr int Nn = Bb * Ss;  // 32768

typedef __attribute__((ext_vector_type(8))) short short8;
typedef __attribute__((ext_vector_type(4))) float f32x4;

__device__ __forceinline__ unsigned short f2bf(float x) {
    unsigned u = __float_as_uint(x);
    unsigned r = (u + 0x7FFFu + ((u >> 16) & 1u)) >> 16;   // RN-even
    return (unsigned short)r;
}
__device__ __forceinline__ float bf2f(unsigned short u) {
    return __uint_as_float((unsigned)u << 16);
}

__device__ __forceinline__ void gload_lds16(const void* g, void* l) {
    __builtin_amdgcn_global_load_lds(
        (const __attribute__((address_space(1))) void*)g,
        (__attribute__((address_space(3))) void*)l, 16, 0, 0);
}

#define BARRIER() do { asm volatile("" ::: "memory"); \
                       __builtin_amdgcn_s_barrier();  \
                       asm volatile("" ::: "memory"); } while (0)

// ---------------- row sum-of-squares (fallback path only) -------------------
__global__ void rows_sq(const float* __restrict__ in, float* __restrict__ out, int nrows) {
    int row  = blockIdx.x * 4 + (threadIdx.x >> 6);
    int lane = threadIdx.x & 63;
    if (row >= nrows) return;
    const float4* p = (const float4*)(in + (size_t)row * Dd);
    float s = 0.f;
    #pragma unroll
    for (int i = 0; i < 2; ++i) {
        float4 v = p[lane + 64 * i];
        s += v.x * v.x + v.y * v.y + v.z * v.z + v.w * v.w;
    }
    #pragma unroll
    for (int off = 32; off; off >>= 1) s += __shfl_down(s, off);
    if (lane == 0) out[row] = s;
}

// ---------------- fused: fp32 -> bf16x2 split (h,m) + row sum-of-squares ---
__global__ void conv_rows(const float* __restrict__ in,
                          unsigned short* __restrict__ ph,
                          unsigned short* __restrict__ pm,
                          float* __restrict__ sq) {
    int row  = blockIdx.x * 4 + (threadIdx.x >> 6);
    int lane = threadIdx.x & 63;
    const float4* p = (const float4*)(in + (size_t)row * Dd);
    ushort4* h4 = (ushort4*)(ph + (size_t)row * Dd);
    ushort4* m4 = (ushort4*)(pm + (size_t)row * Dd);
    float s = 0.f;
    #pragma unroll
    for (int i = 0; i < 2; ++i) {
        int idx = lane + 64 * i;
        float4 v = p[idx];
        float f[4] = {v.x, v.y, v.z, v.w};
        unsigned short hh[4], mm[4];
        #pragma unroll
        for (int j = 0; j < 4; ++j) {
            float x = f[j];
            s += x * x;
            unsigned short a = f2bf(x);
            unsigned short b = f2bf(x - bf2f(a));
            hh[j] = a; mm[j] = b;
        }
        h4[idx] = make_ushort4(hh[0], hh[1], hh[2], hh[3]);
        m4[idx] = make_ushort4(mm[0], mm[1], mm[2], mm[3]);
    }
    #pragma unroll
    for (int off = 32; off; off >>= 1) s += __shfl_down(s, off);
    if (lane == 0) sq[row] = s;
}

// ---------------- bf16x2 4-term MFMA GEMM, 256x256, counted-vmcnt ring -----
// 4 terms {hh,hm,mh,mm}: A parts h,h,m,m; B parts h,m,h,m.
// K_eff = 2048 -> 32 K-tiles of BK=64. 8 waves (2M x 4N), 512 thr.
// A triple-ring (stage t+2: L3/HBM-sourced, 2-tile lead), B double-ring
// (stage t+1: L2-resident embed, 1-tile lead). LDS = 3*32 + 2*32 = 160 KiB.
// Tile end: sched_barrier + vmcnt(4) (A(t+1),B(t+1) landed; A(t+2) stays in
// flight) + barrier. Never drains to 0 in-loop. WAR: every stage overwrites
// a buffer last read >=1 barrier earlier.
__global__ __launch_bounds__(512, 1) void gemm_split256(
    const unsigned short* __restrict__ xp,   // [3][Nn][512] bf16 planes (h,m,-)
    const unsigned short* __restrict__ ep,   // [3][Kk][512]
    const float* __restrict__ xsq,
    const float* __restrict__ esq,
    float* __restrict__ dist,                // [Nn, Kk]
    unsigned long long* __restrict__ packed) // [Nn] argmax accumulator
{
    __shared__ unsigned short As[3][256][64];   // 96 KB
    __shared__ unsigned short Bs[2][256][64];   // 64 KB

    const int tid  = threadIdx.x;
    const int lane = tid & 63;
    const int wid  = tid >> 6;
    const int wr   = wid >> 2;   // 0..1  (M, 128 rows each)
    const int wc   = wid & 3;    // 0..3  (N, 64 cols each)

    // XCD-aware swizzle (nwg = 1024, divisible by 8 -> bijective)
    int bid = blockIdx.x;
    int wg  = (bid & 7) * 128 + (bid >> 3);
    int mb  = wg >> 3, nb = wg & 7;
    const int row0 = mb * 256, col0 = nb * 256;

    f32x4 acc[8][4] = {};
    short8 af[4], afh[4], bl[2], blh[2], bh[2], bhh[2];

    const int l8   = lane >> 3;          // 0..7
    const int csrc = (lane & 7) ^ l8;    // pre-swizzled source chunk

    auto Aplane = [&](int tt) -> const unsigned short* {
        int p = tt >> 3;   // A parts over 32 tiles: h,h,m,m (overrun -> h)
        return xp + (size_t)((p == 2 || p == 3) ? 1 : 0) * ((size_t)Nn * Dd);
    };
    auto Bplane = [&](int tt) -> const unsigned short* {
        int p = tt >> 3;   // B parts: h,m,h,m (overrun -> h)
        return ep + (size_t)((p == 1 || p == 3) ? 1 : 0) * ((size_t)Kk * Dd);
    };

    auto stageAt = [&](const unsigned short* pl, int d, int tt) {
        int ko = (tt & 7) * 64;
        #pragma unroll
        for (int jj = 0; jj < 4; ++jj) {
            int rowbase = jj * 64 + wid * 8;
            const unsigned short* src =
                pl + (size_t)(row0 + rowbase + l8) * Dd + ko + csrc * 8;
            gload_lds16(src, &As[d][rowbase][0]);
        }
    };
    auto stageBt = [&](const unsigned short* pl, int d, int tt) {
        int ko = (tt & 7) * 64;
        #pragma unroll
        for (int jj = 0; jj < 4; ++jj) {
            int rowbase = jj * 64 + wid * 8;
            const unsigned short* src =
                pl + (size_t)(col0 + rowbase + l8) * Dd + ko + csrc * 8;
            gload_lds16(src, &Bs[d][rowbase][0]);
        }
    };

    auto readA4 = [&](int d, int msel) {
        #pragma unroll
        for (int m = 0; m < 4; ++m) {
            int r  = wr * 128 + (msel * 4 + m) * 16 + (lane & 15);
            int c  = ((lane >> 4))     ^ (r & 7);
            int c2 = ((lane >> 4) + 4) ^ (r & 7);
            af[m]  = *(const short8*)&As[d][r][c * 8];
            afh[m] = *(const short8*)&As[d][r][c2 * 8];
        }
    };
    auto readBlo = [&](int d) {
        #pragma unroll
        for (int n = 0; n < 2; ++n) {
            int r  = wc * 64 + n * 16 + (lane & 15);
            int c  = ((lane >> 4))     ^ (r & 7);
            int c2 = ((lane >> 4) + 4) ^ (r & 7);
            bl[n]  = *(const short8*)&Bs[d][r][c * 8];
            blh[n] = *(const short8*)&Bs[d][r][c2 * 8];
        }
    };
    auto readBhi = [&](int d) {
        #pragma unroll
        for (int n = 0; n < 2; ++n) {
            int r  = wc * 64 + (2 + n) * 16 + (lane & 15);
            int c  = ((lane >> 4))     ^ (r & 7);
            int c2 = ((lane >> 4) + 4) ^ (r & 7);
            bh[n]  = *(const short8*)&Bs[d][r][c * 8];
            bhh[n] = *(const short8*)&Bs[d][r][c2 * 8];
        }
    };

    auto mfmaQ = [&](int msel, int nsel, const short8* b0, const short8* b1) {
        #pragma unroll
        for (int m = 0; m < 4; ++m)
            #pragma unroll
            for (int n = 0; n < 2; ++n) {
                int am = msel * 4 + m, bn = nsel * 2 + n;
                acc[am][bn] = __builtin_amdgcn_mfma_f32_16x16x32_bf16(af[m], b0[n], acc[am][bn], 0, 0, 0);
            }
        #pragma unroll
        for (int m = 0; m < 4; ++m)
            #pragma unroll
            for (int n = 0; n < 2; ++n) {
                int am = msel * 4 + m, bn = nsel * 2 + n;
                acc[am][bn] = __builtin_amdgcn_mfma_f32_16x16x32_bf16(afh[m], b1[n], acc[am][bn], 0, 0, 0);
            }
    };

    // prologue: A(0)->ring0, B(0)->ring0, A(1)->ring1; vmcnt(4): A0,B0 landed,
    // A1 stays in flight.
    stageAt(Aplane(0), 0, 0);
    stageBt(Bplane(0), 0, 0);
    stageAt(Aplane(1), 1, 1);
    asm volatile("s_waitcnt vmcnt(4)" ::: "memory");
    BARRIER();

    for (int t = 0; t < 32; ++t) {
        const int ca = t % 3, cb = t & 1;          // current ring slots
        const int nbb = (t + 1) & 1;               // B dest (overwrites B(t-1))
        const int naa = (t + 2) % 3;               // A dest (overwrites A(t-1))

        // stages first: B(t+1) urgent (used next tile), A(t+2) deep prefetch
        stageBt(Bplane(t + 1), nbb, t + 1);
        stageAt(Aplane(t + 2), naa, t + 2);

        readA4(ca, 0); readBlo(cb); readBhi(cb);
        mfmaQ(0, 0, bl, blh);
        mfmaQ(0, 1, bh, bhh);
        readA4(ca, 1);
        mfmaQ(1, 1, bh, bhh);
        mfmaQ(1, 0, bl, blh);

        __builtin_amdgcn_sched_barrier(0);
        // queue: [A(t+1):4, B(t+1):4, A(t+2):4] -> vmcnt(4) completes
        // A(t+1) and B(t+1); A(t+2) remains in flight.
        asm volatile("s_waitcnt vmcnt(4)" ::: "memory");
        BARRIER();
    }
    asm volatile("s_waitcnt vmcnt(0)" ::: "memory");

    // epilogue: dist = 2*dot - xsq - esq ; fused per-row argmax
    const int jrow = (lane >> 4) * 4;
    const int ncol = lane & 15;
    #pragma unroll
    for (int m = 0; m < 8; ++m) {
        int rbase = row0 + wr * 128 + m * 16 + jrow;
        #pragma unroll
        for (int j = 0; j < 4; ++j) {
            int row = rbase + j;
            float xs = xsq[row];
            float best = -3.4e38f; int bi = 0;
            #pragma unroll
            for (int n = 0; n < 4; ++n) {
                int col = col0 + wc * 64 + n * 16 + ncol;
                float v = 2.f * acc[m][n][j] - xs - esq[col];
                dist[(size_t)row * Kk + col] = v;
                if (v > best) { best = v; bi = col; }
            }
            unsigned u = __float_as_uint(best);
            u = (u & 0x80000000u) ? ~u : (u | 0x80000000u);
            unsigned long long pk = ((unsigned long long)u << 32) | (unsigned)(~bi);
            #pragma unroll
            for (int off = 1; off < 16; off <<= 1) {
                unsigned long long o = __shfl_xor(pk, off);
                if (o > pk) pk = o;
            }
            if (ncol == 0) atomicMax(&packed[row], pk);
        }
    }
}

// ---------------- gather/scatter fused with argmax unpack ------------------
__global__ void gather_scatter_packed(const float* __restrict__ x,
                                      const float* __restrict__ embed,
                                      const unsigned long long* __restrict__ packed,
                                      float* __restrict__ quant,
                                      float* __restrict__ ind_f,
                                      float* __restrict__ esum,
                                      int* __restrict__ bins) {
    int n = blockIdx.x;
    int k = (int)(~(unsigned)(packed[n] & 0xFFFFFFFFull));
    int t = threadIdx.x;
    size_t xb = (size_t)n * Dd;
    size_t eb = (size_t)k * Dd;
    float v0 = x[xb + t];
    float v1 = x[xb + t + 256];
    quant[xb + t]       = embed[eb + t];
    quant[xb + t + 256] = embed[eb + t + 256];
    atomicAdd(&esum[eb + t],       v0);
    atomicAdd(&esum[eb + t + 256], v1);
    if (t == 0) { ind_f[n] = (float)k; atomicAdd(&bins[k], 1); }
}

// ---------------- OLD fp32 GEMM + helpers (fallback when ws too small) -----
#define BM 64
#define BN 64
#define BK 32
__global__ __launch_bounds__(256) void gemm_dist(
    const float* __restrict__ A, const float* __restrict__ Bm,
    const float* __restrict__ xsq, const float* __restrict__ esq,
    float* __restrict__ dist)
{
    __shared__ float Asl[BK][BM + 4];
    __shared__ float Bsl[BK][BN + 4];
    int tid = threadIdx.x;
    int row0 = blockIdx.x * BM, col0 = blockIdx.y * BN;
    int tx = tid & 15, ty = tid >> 4;
    float acc[4][4] = {};
    int lr = tid >> 3, lc = (tid & 7) * 4;
    for (int d0 = 0; d0 < Dd; d0 += BK) {
        float4 a0 = *(const float4*)(A  + (size_t)(row0 + lr)      * Dd + d0 + lc);
        float4 a1 = *(const float4*)(A  + (size_t)(row0 + lr + 32) * Dd + d0 + lc);
        float4 b0 = *(const float4*)(Bm + (size_t)(col0 + lr)      * Dd + d0 + lc);
        float4 b1 = *(const float4*)(Bm + (size_t)(col0 + lr + 32) * Dd + d0 + lc);
        __syncthreads();
        Asl[lc + 0][lr] = a0.x; Asl[lc + 1][lr] = a0.y; Asl[lc + 2][lr] = a0.z; Asl[lc + 3][lr] = a0.w;
        Asl[lc + 0][lr + 32] = a1.x; Asl[lc + 1][lr + 32] = a1.y; Asl[lc + 2][lr + 32] = a1.z; Asl[lc + 3][lr + 32] = a1.w;
        Bsl[lc + 0][lr] = b0.x; Bsl[lc + 1][lr] = b0.y; Bsl[lc + 2][lr] = b0.z; Bsl[lc + 3][lr] = b0.w;
        Bsl[lc + 0][lr + 32] = b1.x; Bsl[lc + 1][lr + 32] = b1.y; Bsl[lc + 2][lr + 32] = b1.z; Bsl[lc + 3][lr + 32] = b1.w;
        __syncthreads();
        #pragma unroll
        for (int kd = 0; kd < BK; ++kd) {
            float4 av = *(const float4*)&Asl[kd][ty * 4];
            float4 bv = *(const float4*)&Bsl[kd][tx * 4];
            float a[4] = {av.x, av.y, av.z, av.w};
            float b[4] = {bv.x, bv.y, bv.z, bv.w};
            #pragma unroll
            for (int i = 0; i < 4; ++i)
                #pragma unroll
                for (int j = 0; j < 4; ++j)
                    acc[i][j] = fmaf(a[i], b[j], acc[i][j]);
        }
    }
    #pragma unroll
    for (int i = 0; i < 4; ++i) {
        int row = row0 + ty * 4 + i;
        float xs = xsq[row];
        float4 o;
        int col = col0 + tx * 4;
        o.x = 2.f * acc[i][0] - xs - esq[col + 0];
        o.y = 2.f * acc[i][1] - xs - esq[col + 1];
        o.z = 2.f * acc[i][2] - xs - esq[col + 2];
        o.w = 2.f * acc[i][3] - xs - esq[col + 3];
        *(float4*)(dist + (size_t)row * Kk + col) = o;
    }
}

__global__ void argmax_k(const float* __restrict__ dist,
                         float* __restrict__ ind_f, int* __restrict__ ind_i) {
    int row  = blockIdx.x * 4 + (threadIdx.x >> 6);
    int lane = threadIdx.x & 63;
    const float4* p = (const float4*)(dist + (size_t)row * Kk);
    float best = -3.4e38f;
    int bidx = 0;
    #pragma unroll
    for (int it = 0; it < Kk / 4 / 64; ++it) {
        int i = lane + it * 64;
        float4 v = p[i];
        int base = i * 4;
        if (v.x > best) { best = v.x; bidx = base + 0; }
        if (v.y > best) { best = v.y; bidx = base + 1; }
        if (v.z > best) { best = v.z; bidx = base + 2; }
        if (v.w > best) { best = v.w; bidx = base + 3; }
    }
    #pragma unroll
    for (int off = 32; off; off >>= 1) {
        float ov = __shfl_down(best, off);
        int   oi = __shfl_down(bidx, off);
        if (ov > best || (ov == best && oi < bidx)) { best = ov; bidx = oi; }
    }
    if (lane == 0) { ind_f[row] = (float)bidx; ind_i[row] = bidx; }
}

__global__ void gather_scatter(const float* __restrict__ x,
                               const float* __restrict__ embed,
                               const int* __restrict__ ind,
                               float* __restrict__ quant,
                               float* __restrict__ esum,
                               int* __restrict__ bins) {
    int n = blockIdx.x;
    int k = ind[n];
    int t = threadIdx.x;
    size_t xb = (size_t)n * Dd;
    size_t eb = (size_t)k * Dd;
    float v0 = x[xb + t];
    float v1 = x[xb + t + 256];
    quant[xb + t]       = embed[eb + t];
    quant[xb + t + 256] = embed[eb + t + 256];
    atomicAdd(&esum[eb + t],       v0);
    atomicAdd(&esum[eb + t + 256], v1);
    if (t == 0) atomicAdd(&bins[k], 1);
}

// ---------------- EMA cluster size + laplace total -------------------------
__global__ void finalize1(const float* __restrict__ cs, const int* __restrict__ bins,
                          float* __restrict__ ncs, float* __restrict__ total_ws) {
    __shared__ float red[16];
    int t = threadIdx.x;
    float s = 0.f;
    for (int k = t; k < Kk; k += 1024) {
        float v = cs[k] * DECAY + OMD * (float)bins[k];
        ncs[k] = v;
        s += v;
    }
    #pragma unroll
    for (int off = 32; off; off >>= 1) s += __shfl_down(s, off);
    if ((t & 63) == 0) red[t >> 6] = s;
    __syncthreads();
    if (t == 0) {
        float tot = 0.f;
        #pragma unroll
        for (int i = 0; i < 16; ++i) tot += red[i];
        total_ws[0] = tot;
    }
}

// ---------------- EMA embed_avg + smoothed divide ---------------------------
__global__ void finalize2(const float* __restrict__ ea, const float* __restrict__ esum,
                          const float* __restrict__ ncs, const float* __restrict__ total_ws,
                          float* __restrict__ nea, float* __restrict__ ne) {
    int idx = blockIdx.x * 256 + threadIdx.x;
    float total = total_ws[0];
    int k = idx >> 7;
    float sm = (ncs[k] + EPS) / (total + Kk * EPS) * total;
    float inv = 1.f / sm;
    float4 a = ((const float4*)ea)[idx];
    float4 s = ((const float4*)esum)[idx];
    float4 r;
    r.x = a.x * DECAY + OMD * s.x;
    r.y = a.y * DECAY + OMD * s.y;
    r.z = a.z * DECAY + OMD * s.z;
    r.w = a.w * DECAY + OMD * s.w;
    ((float4*)nea)[idx] = r;
    float4 e;
    e.x = r.x * inv; e.y = r.y * inv; e.z = r.z * inv; e.w = r.w * inv;
    ((float4*)ne)[idx] = e;
}

extern "C" void kernel_launch(void* const* d_in, const int* in_sizes, int n_in,
                              void* d_out, int out_size, void* d_ws, size_t ws_size,
                              hipStream_t stream) {
    const float* x     = (const float*)d_in[0];
    const float* embed = (const float*)d_in[1];
    const float* cs    = (const float*)d_in[2];
    const float* ea    = (const float*)d_in[3];

    float* out     = (float*)d_out;
    float* o_quant = out;
    float* o_ind   = o_quant + (size_t)Nn * Dd;
    float* o_dist  = o_ind + Nn;
    float* o_ncs   = o_dist + (size_t)Nn * Kk;
    float* o_nea   = o_ncs + Kk;
    float* o_ne    = o_nea + (size_t)Kk * Dd;

    // ---- ws layout (3-plane strides kept; plane 2 unused in 4-term path) ----
    size_t xp_elems = (size_t)3 * Nn * Dd;       // bf16
    size_t ep_elems = (size_t)3 * Kk * Dd;
    char* w = (char*)d_ws;
    unsigned short* xp = (unsigned short*)w;                 w += xp_elems * 2;
    unsigned short* epp = (unsigned short*)w;                w += ep_elems * 2;
    float* xsq   = (float*)w;                                w += (size_t)Nn * 4;
    float* esq   = (float*)w;                                w += (size_t)Kk * 4;
    int*   ind_i = (int*)w;                                  w += (size_t)Nn * 4;
    int*   bins  = (int*)w;                                  w += (size_t)Kk * 4;
    float* esum  = (float*)w;                                w += (size_t)Kk * Dd * 4;
    unsigned long long* packed = (unsigned long long*)w;     w += (size_t)Nn * 8;
    float* total = (float*)w;                                w += 256;
    size_t need = (size_t)(w - (char*)d_ws);

    if (ws_size >= need) {
        hipMemsetAsync(bins, 0, (size_t)Kk * 4 + (size_t)Kk * Dd * 4 + (size_t)Nn * 8, stream);

        conv_rows<<<Nn / 4, 256, 0, stream>>>(x, xp, xp + (size_t)Nn * Dd, xsq);
        conv_rows<<<Kk / 4, 256, 0, stream>>>(embed, epp, epp + (size_t)Kk * Dd, esq);

        gemm_split256<<<(Nn / 256) * (Kk / 256), 512, 0, stream>>>(
            xp, epp, xsq, esq, o_dist, packed);

        gather_scatter_packed<<<Nn, 256, 0, stream>>>(
            x, embed, packed, o_quant, o_ind, esum, bins);
    } else {
        float* fxsq  = (float*)d_ws;
        float* fesq  = fxsq + Nn;
        int*   find  = (int*)(fesq + Kk);
        int*   fbins = find + Nn;
        float* fesum = (float*)(fbins + Kk);
        float* ftot  = fesum + (size_t)Kk * Dd;
        xsq = fxsq; esq = fesq; ind_i = find; bins = fbins; esum = fesum; total = ftot;

        hipMemsetAsync(bins, 0, (size_t)(Kk + Kk * Dd) * sizeof(float), stream);
        rows_sq<<<Nn / 4, 256, 0, stream>>>(x, xsq, Nn);
        rows_sq<<<Kk / 4, 256, 0, stream>>>(embed, esq, Kk);
        dim3 g(Nn / BM, Kk / BN);
        gemm_dist<<<g, 256, 0, stream>>>(x, embed, xsq, esq, o_dist);
        argmax_k<<<Nn / 4, 256, 0, stream>>>(o_dist, o_ind, ind_i);
        gather_scatter<<<Nn, 256, 0, stream>>>(x, embed, ind_i, o_quant, esum, bins);
    }

    finalize1<<<1, 1024, 0, stream>>>(cs, bins, o_ncs, total);
    finalize2<<<(Kk * Dd / 4) / 256, 256, 0, stream>>>(ea, esum, o_ncs, total, o_nea, o_ne);
}

// Round 12
// 401.740 us; speedup vs baseline: 1.5067x; 1.0922x over previous
//
#include <hip/hip_runtime.h>

#define DECAY 0.99f
#define OMD   0.01f
#define EPS   1e-5f

constexpr int Bb = 16, Ss = 2048, Dd = 512, Kk = 2048;
constexpr int Nn = Bb * Ss;  // 32768

typedef __attribute__((ext_vector_type(8))) short short8;
typedef __attribute__((ext_vector_type(4))) float f32x4;

__device__ __forceinline__ unsigned short f2bf(float x) {
    unsigned u = __float_as_uint(x);
    unsigned r = (u + 0x7FFFu + ((u >> 16) & 1u)) >> 16;   // RN-even
    return (unsigned short)r;
}
__device__ __forceinline__ float bf2f(unsigned short u) {
    return __uint_as_float((unsigned)u << 16);
}

__device__ __forceinline__ void gload_lds16(const void* g, void* l) {
    __builtin_amdgcn_global_load_lds(
        (const __attribute__((address_space(1))) void*)g,
        (__attribute__((address_space(3))) void*)l, 16, 0, 0);
}

#define BARRIER() do { asm volatile("" ::: "memory"); \
                       __builtin_amdgcn_s_barrier();  \
                       asm volatile("" ::: "memory"); } while (0)

// ---------------- row sum-of-squares (fallback path only) -------------------
__global__ void rows_sq(const float* __restrict__ in, float* __restrict__ out, int nrows) {
    int row  = blockIdx.x * 4 + (threadIdx.x >> 6);
    int lane = threadIdx.x & 63;
    if (row >= nrows) return;
    const float4* p = (const float4*)(in + (size_t)row * Dd);
    float s = 0.f;
    #pragma unroll
    for (int i = 0; i < 2; ++i) {
        float4 v = p[lane + 64 * i];
        s += v.x * v.x + v.y * v.y + v.z * v.z + v.w * v.w;
    }
    #pragma unroll
    for (int off = 32; off; off >>= 1) s += __shfl_down(s, off);
    if (lane == 0) out[row] = s;
}

// ---------------- fused: fp32 -> bf16x2 split (h,m) + row sum-of-squares ---
__global__ void conv_rows(const float* __restrict__ in,
                          unsigned short* __restrict__ ph,
                          unsigned short* __restrict__ pm,
                          float* __restrict__ sq) {
    int row  = blockIdx.x * 4 + (threadIdx.x >> 6);
    int lane = threadIdx.x & 63;
    const float4* p = (const float4*)(in + (size_t)row * Dd);
    ushort4* h4 = (ushort4*)(ph + (size_t)row * Dd);
    ushort4* m4 = (ushort4*)(pm + (size_t)row * Dd);
    float s = 0.f;
    #pragma unroll
    for (int i = 0; i < 2; ++i) {
        int idx = lane + 64 * i;
        float4 v = p[idx];
        float f[4] = {v.x, v.y, v.z, v.w};
        unsigned short hh[4], mm[4];
        #pragma unroll
        for (int j = 0; j < 4; ++j) {
            float x = f[j];
            s += x * x;
            unsigned short a = f2bf(x);
            unsigned short b = f2bf(x - bf2f(a));
            hh[j] = a; mm[j] = b;
        }
        h4[idx] = make_ushort4(hh[0], hh[1], hh[2], hh[3]);
        m4[idx] = make_ushort4(mm[0], mm[1], mm[2], mm[3]);
    }
    #pragma unroll
    for (int off = 32; off; off >>= 1) s += __shfl_down(s, off);
    if (lane == 0) sq[row] = s;
}

// ---------------- bf16x2 4-term GEMM: stage-once-use-4x, BK=32 -------------
// Per raw K-tile (32 cols), stage ALL FOUR plane-tiles {Ah,Am,Bh,Bm} once and
// run all 4 cross-terms (hh,hm,mh,mm) against them. Halves global->LDS
// traffic (1.07 GB vs 2.15) and LDS reads (each staged byte feeds 2 terms).
// 16 raw tiles; r10's proven 1-barrier/tile dbuf structure (stages write only
// the dead slot; single vmcnt(0)+barrier per tile). 8 waves (2M x 4N).
// Swizzle (64B rows): chunk ^= (r ^ (r>>2)) & 3 — <=2-way conflicts, applied
// involutively on gload SOURCE and ds_read (both-sides rule).
__global__ __launch_bounds__(512, 1) void gemm_fused4(
    const unsigned short* __restrict__ xp,   // [3][Nn][512] bf16 planes (h,m,-)
    const unsigned short* __restrict__ ep,   // [3][Kk][512]
    const float* __restrict__ xsq,
    const float* __restrict__ esq,
    float* __restrict__ dist,                // [Nn, Kk]
    unsigned long long* __restrict__ packed) // [Nn] argmax accumulator
{
    __shared__ unsigned short Ah[2][256][32];   // 32 KB
    __shared__ unsigned short Am[2][256][32];   // 32 KB
    __shared__ unsigned short Bh[2][256][32];   // 32 KB
    __shared__ unsigned short Bm[2][256][32];   // 32 KB  -> 128 KB total

    const int tid  = threadIdx.x;
    const int lane = tid & 63;
    const int wid  = tid >> 6;
    const int wr   = wid >> 2;   // 0..1  (M, 128 rows each)
    const int wc   = wid & 3;    // 0..3  (N, 64 cols each)

    // XCD-aware swizzle (nwg = 1024, divisible by 8 -> bijective)
    int bid = blockIdx.x;
    int wg  = (bid & 7) * 128 + (bid >> 3);
    int mb  = wg >> 3, nb = wg & 7;
    const int row0 = mb * 256, col0 = nb * 256;

    f32x4 acc[8][4] = {};

    const unsigned short* xph = xp;
    const unsigned short* xpm = xp + (size_t)Nn * Dd;
    const unsigned short* eph = ep;
    const unsigned short* epm = ep + (size_t)Kk * Dd;

    // stage one 256x32 plane-tile: 2 gloads/thread; 16 rows per wave-instr.
    // LDS dest linear (base + lane*16B); SOURCE chunk pre-swizzled.
    auto stageP = [&](const unsigned short* pl, unsigned short (*dst)[32],
                      int base, int ko) {
        #pragma unroll
        for (int jj = 0; jj < 2; ++jj) {
            int rowbase = jj * 128 + wid * 16;
            int row = rowbase + (lane >> 2);
            int sc = (lane & 3) ^ ((row ^ (row >> 2)) & 3);
            const unsigned short* src =
                pl + (size_t)(base + row) * Dd + ko + sc * 8;
            gload_lds16(src, &dst[rowbase][0]);
        }
    };

    auto readAfr = [&](unsigned short (*S)[32], int msel, short8* out) {
        #pragma unroll
        for (int m = 0; m < 4; ++m) {
            int r = wr * 128 + (msel * 4 + m) * 16 + (lane & 15);
            int c = (lane >> 4) ^ ((r ^ (r >> 2)) & 3);
            out[m] = *(const short8*)&S[r][c * 8];
        }
    };
    auto readBfr = [&](unsigned short (*S)[32], short8* out) {
        #pragma unroll
        for (int n = 0; n < 4; ++n) {
            int r = wc * 64 + n * 16 + (lane & 15);
            int c = (lane >> 4) ^ ((r ^ (r >> 2)) & 3);
            out[n] = *(const short8*)&S[r][c * 8];
        }
    };

    // prologue: stage tile 0 into slot 0
    stageP(xph, Ah[0], row0, 0);
    stageP(xpm, Am[0], row0, 0);
    stageP(eph, Bh[0], col0, 0);
    stageP(epm, Bm[0], col0, 0);
    asm volatile("s_waitcnt vmcnt(0)" ::: "memory");
    BARRIER();

    for (int t = 0; t < 16; ++t) {
        const int cur = t & 1, nxt = cur ^ 1;
        if (t < 15) {
            int kon = (t + 1) * 32;
            stageP(xph, Ah[nxt], row0, kon);
            stageP(xpm, Am[nxt], row0, kon);
            stageP(eph, Bh[nxt], col0, kon);
            stageP(epm, Bm[nxt], col0, kon);
        }

        short8 vbh[4], vbm[4];
        readBfr(Bh[cur], vbh);
        readBfr(Bm[cur], vbm);

        #pragma unroll
        for (int ms = 0; ms < 2; ++ms) {
            short8 vah[4], vam[4];
            readAfr(Ah[cur], ms, vah);
            readAfr(Am[cur], ms, vam);
            #pragma unroll
            for (int m = 0; m < 4; ++m)
                #pragma unroll
                for (int n = 0; n < 4; ++n)
                    acc[ms * 4 + m][n] = __builtin_amdgcn_mfma_f32_16x16x32_bf16(
                        vah[m], vbh[n], acc[ms * 4 + m][n], 0, 0, 0);
            #pragma unroll
            for (int m = 0; m < 4; ++m)
                #pragma unroll
                for (int n = 0; n < 4; ++n)
                    acc[ms * 4 + m][n] = __builtin_amdgcn_mfma_f32_16x16x32_bf16(
                        vah[m], vbm[n], acc[ms * 4 + m][n], 0, 0, 0);
            #pragma unroll
            for (int m = 0; m < 4; ++m)
                #pragma unroll
                for (int n = 0; n < 4; ++n)
                    acc[ms * 4 + m][n] = __builtin_amdgcn_mfma_f32_16x16x32_bf16(
                        vam[m], vbh[n], acc[ms * 4 + m][n], 0, 0, 0);
            #pragma unroll
            for (int m = 0; m < 4; ++m)
                #pragma unroll
                for (int n = 0; n < 4; ++n)
                    acc[ms * 4 + m][n] = __builtin_amdgcn_mfma_f32_16x16x32_bf16(
                        vam[m], vbm[n], acc[ms * 4 + m][n], 0, 0, 0);
        }

        asm volatile("s_waitcnt vmcnt(0)" ::: "memory");
        BARRIER();
    }

    // epilogue: dist = 2*dot - xsq - esq ; fused per-row argmax
    const int jrow = (lane >> 4) * 4;
    const int ncol = lane & 15;
    #pragma unroll
    for (int m = 0; m < 8; ++m) {
        int rbase = row0 + wr * 128 + m * 16 + jrow;
        #pragma unroll
        for (int j = 0; j < 4; ++j) {
            int row = rbase + j;
            float xs = xsq[row];
            float best = -3.4e38f; int bi = 0;
            #pragma unroll
            for (int n = 0; n < 4; ++n) {
                int col = col0 + wc * 64 + n * 16 + ncol;
                float v = 2.f * acc[m][n][j] - xs - esq[col];
                dist[(size_t)row * Kk + col] = v;
                if (v > best) { best = v; bi = col; }
            }
            unsigned u = __float_as_uint(best);
            u = (u & 0x80000000u) ? ~u : (u | 0x80000000u);
            unsigned long long pk = ((unsigned long long)u << 32) | (unsigned)(~bi);
            #pragma unroll
            for (int off = 1; off < 16; off <<= 1) {
                unsigned long long o = __shfl_xor(pk, off);
                if (o > pk) pk = o;
            }
            if (ncol == 0) atomicMax(&packed[row], pk);
        }
    }
}

// ---------------- gather/scatter fused with argmax unpack ------------------
__global__ void gather_scatter_packed(const float* __restrict__ x,
                                      const float* __restrict__ embed,
                                      const unsigned long long* __restrict__ packed,
                                      float* __restrict__ quant,
                                      float* __restrict__ ind_f,
                                      float* __restrict__ esum,
                                      int* __restrict__ bins) {
    int n = blockIdx.x;
    int k = (int)(~(unsigned)(packed[n] & 0xFFFFFFFFull));
    int t = threadIdx.x;
    size_t xb = (size_t)n * Dd;
    size_t eb = (size_t)k * Dd;
    float v0 = x[xb + t];
    float v1 = x[xb + t + 256];
    quant[xb + t]       = embed[eb + t];
    quant[xb + t + 256] = embed[eb + t + 256];
    atomicAdd(&esum[eb + t],       v0);
    atomicAdd(&esum[eb + t + 256], v1);
    if (t == 0) { ind_f[n] = (float)k; atomicAdd(&bins[k], 1); }
}

// ---------------- OLD fp32 GEMM + helpers (fallback when ws too small) -----
#define BM 64
#define BN 64
#define BK 32
__global__ __launch_bounds__(256) void gemm_dist(
    const float* __restrict__ A, const float* __restrict__ Bm_,
    const float* __restrict__ xsq, const float* __restrict__ esq,
    float* __restrict__ dist)
{
    __shared__ float Asl[BK][BM + 4];
    __shared__ float Bsl[BK][BN + 4];
    int tid = threadIdx.x;
    int row0 = blockIdx.x * BM, col0 = blockIdx.y * BN;
    int tx = tid & 15, ty = tid >> 4;
    float acc[4][4] = {};
    int lr = tid >> 3, lc = (tid & 7) * 4;
    for (int d0 = 0; d0 < Dd; d0 += BK) {
        float4 a0 = *(const float4*)(A   + (size_t)(row0 + lr)      * Dd + d0 + lc);
        float4 a1 = *(const float4*)(A   + (size_t)(row0 + lr + 32) * Dd + d0 + lc);
        float4 b0 = *(const float4*)(Bm_ + (size_t)(col0 + lr)      * Dd + d0 + lc);
        float4 b1 = *(const float4*)(Bm_ + (size_t)(col0 + lr + 32) * Dd + d0 + lc);
        __syncthreads();
        Asl[lc + 0][lr] = a0.x; Asl[lc + 1][lr] = a0.y; Asl[lc + 2][lr] = a0.z; Asl[lc + 3][lr] = a0.w;
        Asl[lc + 0][lr + 32] = a1.x; Asl[lc + 1][lr + 32] = a1.y; Asl[lc + 2][lr + 32] = a1.z; Asl[lc + 3][lr + 32] = a1.w;
        Bsl[lc + 0][lr] = b0.x; Bsl[lc + 1][lr] = b0.y; Bsl[lc + 2][lr] = b0.z; Bsl[lc + 3][lr] = b0.w;
        Bsl[lc + 0][lr + 32] = b1.x; Bsl[lc + 1][lr + 32] = b1.y; Bsl[lc + 2][lr + 32] = b1.z; Bsl[lc + 3][lr + 32] = b1.w;
        __syncthreads();
        #pragma unroll
        for (int kd = 0; kd < BK; ++kd) {
            float4 av = *(const float4*)&Asl[kd][ty * 4];
            float4 bv = *(const float4*)&Bsl[kd][tx * 4];
            float a[4] = {av.x, av.y, av.z, av.w};
            float b[4] = {bv.x, bv.y, bv.z, bv.w};
            #pragma unroll
            for (int i = 0; i < 4; ++i)
                #pragma unroll
                for (int j = 0; j < 4; ++j)
                    acc[i][j] = fmaf(a[i], b[j], acc[i][j]);
        }
    }
    #pragma unroll
    for (int i = 0; i < 4; ++i) {
        int row = row0 + ty * 4 + i;
        float xs = xsq[row];
        float4 o;
        int col = col0 + tx * 4;
        o.x = 2.f * acc[i][0] - xs - esq[col + 0];
        o.y = 2.f * acc[i][1] - xs - esq[col + 1];
        o.z = 2.f * acc[i][2] - xs - esq[col + 2];
        o.w = 2.f * acc[i][3] - xs - esq[col + 3];
        *(float4*)(dist + (size_t)row * Kk + col) = o;
    }
}

__global__ void argmax_k(const float* __restrict__ dist,
                         float* __restrict__ ind_f, int* __restrict__ ind_i) {
    int row  = blockIdx.x * 4 + (threadIdx.x >> 6);
    int lane = threadIdx.x & 63;
    const float4* p = (const float4*)(dist + (size_t)row * Kk);
    float best = -3.4e38f;
    int bidx = 0;
    #pragma unroll
    for (int it = 0; it < Kk / 4 / 64; ++it) {
        int i = lane + it * 64;
        float4 v = p[i];
        int base = i * 4;
        if (v.x > best) { best = v.x; bidx = base + 0; }
        if (v.y > best) { best = v.y; bidx = base + 1; }
        if (v.z > best) { best = v.z; bidx = base + 2; }
        if (v.w > best) { best = v.w; bidx = base + 3; }
    }
    #pragma unroll
    for (int off = 32; off; off >>= 1) {
        float ov = __shfl_down(best, off);
        int   oi = __shfl_down(bidx, off);
        if (ov > best || (ov == best && oi < bidx)) { best = ov; bidx = oi; }
    }
    if (lane == 0) { ind_f[row] = (float)bidx; ind_i[row] = bidx; }
}

__global__ void gather_scatter(const float* __restrict__ x,
                               const float* __restrict__ embed,
                               const int* __restrict__ ind,
                               float* __restrict__ quant,
                               float* __restrict__ esum,
                               int* __restrict__ bins) {
    int n = blockIdx.x;
    int k = ind[n];
    int t = threadIdx.x;
    size_t xb = (size_t)n * Dd;
    size_t eb = (size_t)k * Dd;
    float v0 = x[xb + t];
    float v1 = x[xb + t + 256];
    quant[xb + t]       = embed[eb + t];
    quant[xb + t + 256] = embed[eb + t + 256];
    atomicAdd(&esum[eb + t],       v0);
    atomicAdd(&esum[eb + t + 256], v1);
    if (t == 0) atomicAdd(&bins[k], 1);
}

// ---------------- EMA cluster size + laplace total -------------------------
__global__ void finalize1(const float* __restrict__ cs, const int* __restrict__ bins,
                          float* __restrict__ ncs, float* __restrict__ total_ws) {
    __shared__ float red[16];
    int t = threadIdx.x;
    float s = 0.f;
    for (int k = t; k < Kk; k += 1024) {
        float v = cs[k] * DECAY + OMD * (float)bins[k];
        ncs[k] = v;
        s += v;
    }
    #pragma unroll
    for (int off = 32; off; off >>= 1) s += __shfl_down(s, off);
    if ((t & 63) == 0) red[t >> 6] = s;
    __syncthreads();
    if (t == 0) {
        float tot = 0.f;
        #pragma unroll
        for (int i = 0; i < 16; ++i) tot += red[i];
        total_ws[0] = tot;
    }
}

// ---------------- EMA embed_avg + smoothed divide ---------------------------
__global__ void finalize2(const float* __restrict__ ea, const float* __restrict__ esum,
                          const float* __restrict__ ncs, const float* __restrict__ total_ws,
                          float* __restrict__ nea, float* __restrict__ ne) {
    int idx = blockIdx.x * 256 + threadIdx.x;
    float total = total_ws[0];
    int k = idx >> 7;
    float sm = (ncs[k] + EPS) / (total + Kk * EPS) * total;
    float inv = 1.f / sm;
    float4 a = ((const float4*)ea)[idx];
    float4 s = ((const float4*)esum)[idx];
    float4 r;
    r.x = a.x * DECAY + OMD * s.x;
    r.y = a.y * DECAY + OMD * s.y;
    r.z = a.z * DECAY + OMD * s.z;
    r.w = a.w * DECAY + OMD * s.w;
    ((float4*)nea)[idx] = r;
    float4 e;
    e.x = r.x * inv; e.y = r.y * inv; e.z = r.z * inv; e.w = r.w * inv;
    ((float4*)ne)[idx] = e;
}

extern "C" void kernel_launch(void* const* d_in, const int* in_sizes, int n_in,
                              void* d_out, int out_size, void* d_ws, size_t ws_size,
                              hipStream_t stream) {
    const float* x     = (const float*)d_in[0];
    const float* embed = (const float*)d_in[1];
    const float* cs    = (const float*)d_in[2];
    const float* ea    = (const float*)d_in[3];

    float* out     = (float*)d_out;
    float* o_quant = out;
    float* o_ind   = o_quant + (size_t)Nn * Dd;
    float* o_dist  = o_ind + Nn;
    float* o_ncs   = o_dist + (size_t)Nn * Kk;
    float* o_nea   = o_ncs + Kk;
    float* o_ne    = o_nea + (size_t)Kk * Dd;

    // ---- ws layout (3-plane strides kept; plane 2 unused in 4-term path) ----
    size_t xp_elems = (size_t)3 * Nn * Dd;       // bf16
    size_t ep_elems = (size_t)3 * Kk * Dd;
    char* w = (char*)d_ws;
    unsigned short* xp = (unsigned short*)w;                 w += xp_elems * 2;
    unsigned short* epp = (unsigned short*)w;                w += ep_elems * 2;
    float* xsq   = (float*)w;                                w += (size_t)Nn * 4;
    float* esq   = (float*)w;                                w += (size_t)Kk * 4;
    int*   ind_i = (int*)w;                                  w += (size_t)Nn * 4;
    int*   bins  = (int*)w;                                  w += (size_t)Kk * 4;
    float* esum  = (float*)w;                                w += (size_t)Kk * Dd * 4;
    unsigned long long* packed = (unsigned long long*)w;     w += (size_t)Nn * 8;
    float* total = (float*)w;                                w += 256;
    size_t need = (size_t)(w - (char*)d_ws);

    if (ws_size >= need) {
        hipMemsetAsync(bins, 0, (size_t)Kk * 4 + (size_t)Kk * Dd * 4 + (size_t)Nn * 8, stream);

        conv_rows<<<Nn / 4, 256, 0, stream>>>(x, xp, xp + (size_t)Nn * Dd, xsq);
        conv_rows<<<Kk / 4, 256, 0, stream>>>(embed, epp, epp + (size_t)Kk * Dd, esq);

        gemm_fused4<<<(Nn / 256) * (Kk / 256), 512, 0, stream>>>(
            xp, epp, xsq, esq, o_dist, packed);

        gather_scatter_packed<<<Nn, 256, 0, stream>>>(
            x, embed, packed, o_quant, o_ind, esum, bins);
    } else {
        float* fxsq  = (float*)d_ws;
        float* fesq  = fxsq + Nn;
        int*   find  = (int*)(fesq + Kk);
        int*   fbins = find + Nn;
        float* fesum = (float*)(fbins + Kk);
        float* ftot  = fesum + (size_t)Kk * Dd;
        xsq = fxsq; esq = fesq; ind_i = find; bins = fbins; esum = fesum; total = ftot;

        hipMemsetAsync(bins, 0, (size_t)(Kk + Kk * Dd) * sizeof(float), stream);
        rows_sq<<<Nn / 4, 256, 0, stream>>>(x, xsq, Nn);
        rows_sq<<<Kk / 4, 256, 0, stream>>>(embed, esq, Kk);
        dim3 g(Nn / BM, Kk / BN);
        gemm_dist<<<g, 256, 0, stream>>>(x, embed, xsq, esq, o_dist);
        argmax_k<<<Nn / 4, 256, 0, stream>>>(o_dist, o_ind, ind_i);
        gather_scatter<<<Nn, 256, 0, stream>>>(x, embed, ind_i, o_quant, esum, bins);
    }

    finalize1<<<1, 1024, 0, stream>>>(cs, bins, o_ncs, total);
    finalize2<<<(Kk * Dd / 4) / 256, 256, 0, stream>>>(ea, esum, o_ncs, total, o_nea, o_ne);
}

// Round 13
// 388.740 us; speedup vs baseline: 1.5571x; 1.0334x over previous
//
#include <hip/hip_runtime.h>

#define DECAY 0.99f
#define OMD   0.01f
#define EPS   1e-5f

constexpr int Bb = 16, Ss = 2048, Dd = 512, Kk = 2048;
constexpr int Nn = Bb * Ss;  // 32768

typedef __attribute__((ext_vector_type(8))) short short8;
typedef __attribute__((ext_vector_type(4))) float f32x4;

__device__ __forceinline__ unsigned short f2bf(float x) {
    unsigned u = __float_as_uint(x);
    unsigned r = (u + 0x7FFFu + ((u >> 16) & 1u)) >> 16;   // RN-even
    return (unsigned short)r;
}
__device__ __forceinline__ float bf2f(unsigned short u) {
    return __uint_as_float((unsigned)u << 16);
}

__device__ __forceinline__ void gload_lds16(const void* g, void* l) {
    __builtin_amdgcn_global_load_lds(
        (const __attribute__((address_space(1))) void*)g,
        (__attribute__((address_space(3))) void*)l, 16, 0, 0);
}

// pair-swap the u16 lanes of each dword: [h0 m0 h1 m1 ...] -> [m0 h0 m1 h1 ...]
__device__ __forceinline__ short8 swap16(short8 v) {
    union { short8 s; unsigned u[4]; } a, b;
    a.s = v;
    #pragma unroll
    for (int i = 0; i < 4; ++i) b.u[i] = (a.u[i] >> 16) | (a.u[i] << 16);
    return b.s;
}

#define BARRIER() do { asm volatile("" ::: "memory"); \
                       __builtin_amdgcn_s_barrier();  \
                       asm volatile("" ::: "memory"); } while (0)

// ---------------- row sum-of-squares (fallback path only) -------------------
__global__ void rows_sq(const float* __restrict__ in, float* __restrict__ out, int nrows) {
    int row  = blockIdx.x * 4 + (threadIdx.x >> 6);
    int lane = threadIdx.x & 63;
    if (row >= nrows) return;
    const float4* p = (const float4*)(in + (size_t)row * Dd);
    float s = 0.f;
    #pragma unroll
    for (int i = 0; i < 2; ++i) {
        float4 v = p[lane + 64 * i];
        s += v.x * v.x + v.y * v.y + v.z * v.z + v.w * v.w;
    }
    #pragma unroll
    for (int off = 32; off; off >>= 1) s += __shfl_down(s, off);
    if (lane == 0) out[row] = s;
}

// ------- fused: fp32 -> k-interleaved bf16 (h,m) plane + row sum-of-squares -
// out[row][2k] = h_k, out[row][2k+1] = m_k  (row = 1024 elems = 2 KB)
__global__ void conv_ilv(const float* __restrict__ in,
                         unsigned short* __restrict__ out,
                         float* __restrict__ sq) {
    int row  = blockIdx.x * 4 + (threadIdx.x >> 6);
    int lane = threadIdx.x & 63;
    const float4* p = (const float4*)(in + (size_t)row * Dd);
    uint4* o = (uint4*)(out + (size_t)row * 1024);
    float s = 0.f;
    #pragma unroll
    for (int i = 0; i < 2; ++i) {
        int idx = lane + 64 * i;
        float4 v = p[idx];
        float f[4] = {v.x, v.y, v.z, v.w};
        unsigned d[4];
        #pragma unroll
        for (int j = 0; j < 4; ++j) {
            float x = f[j];
            s += x * x;
            unsigned short h = f2bf(x);
            unsigned short m = f2bf(x - bf2f(h));
            d[j] = ((unsigned)m << 16) | h;
        }
        o[idx] = make_uint4(d[0], d[1], d[2], d[3]);
    }
    #pragma unroll
    for (int off = 32; off; off >>= 1) s += __shfl_down(s, off);
    if (lane == 0) sq[row] = s;
}

// -------- bf16x2 4-term GEMM via k-interleaved planes, 256x256, dbuf -------
// One raw K-tile (32 cols) = 64 interleaved elems = 128B contiguous per row.
// dot(a', b')  = hh + mm ;  dot(a', swap16(b')) = hm + mh  -> all 4 terms,
// one staged copy of each operand. 16 raw tiles. r10's proven structure:
// stage-first into dead buffer, single vmcnt(0)+barrier per tile; 128B-row
// XOR-(r&7) swizzle (both-sides) = zero bank conflicts. 8 waves (2M x 4N).
__global__ __launch_bounds__(512, 1) void gemm_ilv(
    const unsigned short* __restrict__ xhm,  // [Nn][1024] interleaved (h,m)
    const unsigned short* __restrict__ ehm,  // [Kk][1024]
    const float* __restrict__ xsq,
    const float* __restrict__ esq,
    float* __restrict__ dist,                // [Nn, Kk]
    unsigned long long* __restrict__ packed) // [Nn] argmax accumulator
{
    __shared__ unsigned short As[2][256][64];   // 64 KB
    __shared__ unsigned short Bs[2][256][64];   // 64 KB

    const int tid  = threadIdx.x;
    const int lane = tid & 63;
    const int wid  = tid >> 6;
    const int wr   = wid >> 2;   // 0..1  (M, 128 rows each)
    const int wc   = wid & 3;    // 0..3  (N, 64 cols each)

    // XCD-aware swizzle (nwg = 1024, divisible by 8 -> bijective)
    int bid = blockIdx.x;
    int wg  = (bid & 7) * 128 + (bid >> 3);
    int mb  = wg >> 3, nb = wg & 7;
    const int row0 = mb * 256, col0 = nb * 256;

    f32x4 acc[8][4] = {};

    const int l8   = lane >> 3;          // 0..7
    const int csrc = (lane & 7) ^ l8;    // pre-swizzled source chunk

    // stage one 256x64-elem interleaved tile (32 KB): 4 gloads/thread
    auto stageT = [&](const unsigned short* pl, unsigned short (*dst)[64],
                      int base, int t) {
        #pragma unroll
        for (int jj = 0; jj < 4; ++jj) {
            int rowbase = jj * 64 + wid * 8;
            int row = rowbase + l8;
            const unsigned short* src =
                pl + (size_t)(base + row) * 1024 + t * 64 + csrc * 8;
            gload_lds16(src, &dst[rowbase][0]);
        }
    };

    auto readA = [&](int d, int g, short8* out) {   // 8 m-frags for kgroup g
        #pragma unroll
        for (int m = 0; m < 8; ++m) {
            int r = wr * 128 + m * 16 + (lane & 15);
            int c = (g * 4 + (lane >> 4)) ^ (r & 7);
            out[m] = *(const short8*)&As[d][r][c * 8];
        }
    };
    auto readB = [&](int d, int g, short8* out) {   // 4 n-frags for kgroup g
        #pragma unroll
        for (int n = 0; n < 4; ++n) {
            int r = wc * 64 + n * 16 + (lane & 15);
            int c = (g * 4 + (lane >> 4)) ^ (r & 7);
            out[n] = *(const short8*)&Bs[d][r][c * 8];
        }
    };

    // prologue: stage tile 0 into slot 0
    stageT(xhm, As[0], row0, 0);
    stageT(ehm, Bs[0], col0, 0);
    asm volatile("s_waitcnt vmcnt(0)" ::: "memory");
    BARRIER();

    for (int t = 0; t < 16; ++t) {
        const int cur = t & 1, nxt = cur ^ 1;
        if (t < 15) {
            stageT(xhm, As[nxt], row0, t + 1);
            stageT(ehm, Bs[nxt], col0, t + 1);
        }

        #pragma unroll
        for (int g = 0; g < 2; ++g) {
            short8 va[8], vb[4], vb2[4];
            readA(cur, g, va);
            readB(cur, g, vb);
            #pragma unroll
            for (int n = 0; n < 4; ++n) vb2[n] = swap16(vb[n]);
            #pragma unroll
            for (int m = 0; m < 8; ++m)
                #pragma unroll
                for (int n = 0; n < 4; ++n)
                    acc[m][n] = __builtin_amdgcn_mfma_f32_16x16x32_bf16(
                        va[m], vb[n], acc[m][n], 0, 0, 0);   // hh + mm
            #pragma unroll
            for (int m = 0; m < 8; ++m)
                #pragma unroll
                for (int n = 0; n < 4; ++n)
                    acc[m][n] = __builtin_amdgcn_mfma_f32_16x16x32_bf16(
                        va[m], vb2[n], acc[m][n], 0, 0, 0);  // hm + mh
        }

        asm volatile("s_waitcnt vmcnt(0)" ::: "memory");
        BARRIER();
    }

    // epilogue: dist = 2*dot - xsq - esq ; fused per-row argmax
    const int jrow = (lane >> 4) * 4;
    const int ncol = lane & 15;
    #pragma unroll
    for (int m = 0; m < 8; ++m) {
        int rbase = row0 + wr * 128 + m * 16 + jrow;
        #pragma unroll
        for (int j = 0; j < 4; ++j) {
            int row = rbase + j;
            float xs = xsq[row];
            float best = -3.4e38f; int bi = 0;
            #pragma unroll
            for (int n = 0; n < 4; ++n) {
                int col = col0 + wc * 64 + n * 16 + ncol;
                float v = 2.f * acc[m][n][j] - xs - esq[col];
                dist[(size_t)row * Kk + col] = v;
                if (v > best) { best = v; bi = col; }
            }
            unsigned u = __float_as_uint(best);
            u = (u & 0x80000000u) ? ~u : (u | 0x80000000u);
            unsigned long long pk = ((unsigned long long)u << 32) | (unsigned)(~bi);
            #pragma unroll
            for (int off = 1; off < 16; off <<= 1) {
                unsigned long long o = __shfl_xor(pk, off);
                if (o > pk) pk = o;
            }
            if (ncol == 0) atomicMax(&packed[row], pk);
        }
    }
}

// ---------------- gather/scatter fused with argmax unpack ------------------
__global__ void gather_scatter_packed(const float* __restrict__ x,
                                      const float* __restrict__ embed,
                                      const unsigned long long* __restrict__ packed,
                                      float* __restrict__ quant,
                                      float* __restrict__ ind_f,
                                      float* __restrict__ esum,
                                      int* __restrict__ bins) {
    int n = blockIdx.x;
    int k = (int)(~(unsigned)(packed[n] & 0xFFFFFFFFull));
    int t = threadIdx.x;
    size_t xb = (size_t)n * Dd;
    size_t eb = (size_t)k * Dd;
    float v0 = x[xb + t];
    float v1 = x[xb + t + 256];
    quant[xb + t]       = embed[eb + t];
    quant[xb + t + 256] = embed[eb + t + 256];
    atomicAdd(&esum[eb + t],       v0);
    atomicAdd(&esum[eb + t + 256], v1);
    if (t == 0) { ind_f[n] = (float)k; atomicAdd(&bins[k], 1); }
}

// ---------------- OLD fp32 GEMM + helpers (fallback when ws too small) -----
#define BM 64
#define BN 64
#define BK 32
__global__ __launch_bounds__(256) void gemm_dist(
    const float* __restrict__ A, const float* __restrict__ Bm_,
    const float* __restrict__ xsq, const float* __restrict__ esq,
    float* __restrict__ dist)
{
    __shared__ float Asl[BK][BM + 4];
    __shared__ float Bsl[BK][BN + 4];
    int tid = threadIdx.x;
    int row0 = blockIdx.x * BM, col0 = blockIdx.y * BN;
    int tx = tid & 15, ty = tid >> 4;
    float acc[4][4] = {};
    int lr = tid >> 3, lc = (tid & 7) * 4;
    for (int d0 = 0; d0 < Dd; d0 += BK) {
        float4 a0 = *(const float4*)(A   + (size_t)(row0 + lr)      * Dd + d0 + lc);
        float4 a1 = *(const float4*)(A   + (size_t)(row0 + lr + 32) * Dd + d0 + lc);
        float4 b0 = *(const float4*)(Bm_ + (size_t)(col0 + lr)      * Dd + d0 + lc);
        float4 b1 = *(const float4*)(Bm_ + (size_t)(col0 + lr + 32) * Dd + d0 + lc);
        __syncthreads();
        Asl[lc + 0][lr] = a0.x; Asl[lc + 1][lr] = a0.y; Asl[lc + 2][lr] = a0.z; Asl[lc + 3][lr] = a0.w;
        Asl[lc + 0][lr + 32] = a1.x; Asl[lc + 1][lr + 32] = a1.y; Asl[lc + 2][lr + 32] = a1.z; Asl[lc + 3][lr + 32] = a1.w;
        Bsl[lc + 0][lr] = b0.x; Bsl[lc + 1][lr] = b0.y; Bsl[lc + 2][lr] = b0.z; Bsl[lc + 3][lr] = b0.w;
        Bsl[lc + 0][lr + 32] = b1.x; Bsl[lc + 1][lr + 32] = b1.y; Bsl[lc + 2][lr + 32] = b1.z; Bsl[lc + 3][lr + 32] = b1.w;
        __syncthreads();
        #pragma unroll
        for (int kd = 0; kd < BK; ++kd) {
            float4 av = *(const float4*)&Asl[kd][ty * 4];
            float4 bv = *(const float4*)&Bsl[kd][tx * 4];
            float a[4] = {av.x, av.y, av.z, av.w};
            float b[4] = {bv.x, bv.y, bv.z, bv.w};
            #pragma unroll
            for (int i = 0; i < 4; ++i)
                #pragma unroll
                for (int j = 0; j < 4; ++j)
                    acc[i][j] = fmaf(a[i], b[j], acc[i][j]);
        }
    }
    #pragma unroll
    for (int i = 0; i < 4; ++i) {
        int row = row0 + ty * 4 + i;
        float xs = xsq[row];
        float4 o;
        int col = col0 + tx * 4;
        o.x = 2.f * acc[i][0] - xs - esq[col + 0];
        o.y = 2.f * acc[i][1] - xs - esq[col + 1];
        o.z = 2.f * acc[i][2] - xs - esq[col + 2];
        o.w = 2.f * acc[i][3] - xs - esq[col + 3];
        *(float4*)(dist + (size_t)row * Kk + col) = o;
    }
}

__global__ void argmax_k(const float* __restrict__ dist,
                         float* __restrict__ ind_f, int* __restrict__ ind_i) {
    int row  = blockIdx.x * 4 + (threadIdx.x >> 6);
    int lane = threadIdx.x & 63;
    const float4* p = (const float4*)(dist + (size_t)row * Kk);
    float best = -3.4e38f;
    int bidx = 0;
    #pragma unroll
    for (int it = 0; it < Kk / 4 / 64; ++it) {
        int i = lane + it * 64;
        float4 v = p[i];
        int base = i * 4;
        if (v.x > best) { best = v.x; bidx = base + 0; }
        if (v.y > best) { best = v.y; bidx = base + 1; }
        if (v.z > best) { best = v.z; bidx = base + 2; }
        if (v.w > best) { best = v.w; bidx = base + 3; }
    }
    #pragma unroll
    for (int off = 32; off; off >>= 1) {
        float ov = __shfl_down(best, off);
        int   oi = __shfl_down(bidx, off);
        if (ov > best || (ov == best && oi < bidx)) { best = ov; bidx = oi; }
    }
    if (lane == 0) { ind_f[row] = (float)bidx; ind_i[row] = bidx; }
}

__global__ void gather_scatter(const float* __restrict__ x,
                               const float* __restrict__ embed,
                               const int* __restrict__ ind,
                               float* __restrict__ quant,
                               float* __restrict__ esum,
                               int* __restrict__ bins) {
    int n = blockIdx.x;
    int k = ind[n];
    int t = threadIdx.x;
    size_t xb = (size_t)n * Dd;
    size_t eb = (size_t)k * Dd;
    float v0 = x[xb + t];
    float v1 = x[xb + t + 256];
    quant[xb + t]       = embed[eb + t];
    quant[xb + t + 256] = embed[eb + t + 256];
    atomicAdd(&esum[eb + t],       v0);
    atomicAdd(&esum[eb + t + 256], v1);
    if (t == 0) atomicAdd(&bins[k], 1);
}

// ---------------- EMA cluster size + laplace total -------------------------
__global__ void finalize1(const float* __restrict__ cs, const int* __restrict__ bins,
                          float* __restrict__ ncs, float* __restrict__ total_ws) {
    __shared__ float red[16];
    int t = threadIdx.x;
    float s = 0.f;
    for (int k = t; k < Kk; k += 1024) {
        float v = cs[k] * DECAY + OMD * (float)bins[k];
        ncs[k] = v;
        s += v;
    }
    #pragma unroll
    for (int off = 32; off; off >>= 1) s += __shfl_down(s, off);
    if ((t & 63) == 0) red[t >> 6] = s;
    __syncthreads();
    if (t == 0) {
        float tot = 0.f;
        #pragma unroll
        for (int i = 0; i < 16; ++i) tot += red[i];
        total_ws[0] = tot;
    }
}

// ---------------- EMA embed_avg + smoothed divide ---------------------------
__global__ void finalize2(const float* __restrict__ ea, const float* __restrict__ esum,
                          const float* __restrict__ ncs, const float* __restrict__ total_ws,
                          float* __restrict__ nea, float* __restrict__ ne) {
    int idx = blockIdx.x * 256 + threadIdx.x;
    float total = total_ws[0];
    int k = idx >> 7;
    float sm = (ncs[k] + EPS) / (total + Kk * EPS) * total;
    float inv = 1.f / sm;
    float4 a = ((const float4*)ea)[idx];
    float4 s = ((const float4*)esum)[idx];
    float4 r;
    r.x = a.x * DECAY + OMD * s.x;
    r.y = a.y * DECAY + OMD * s.y;
    r.z = a.z * DECAY + OMD * s.z;
    r.w = a.w * DECAY + OMD * s.w;
    ((float4*)nea)[idx] = r;
    float4 e;
    e.x = r.x * inv; e.y = r.y * inv; e.z = r.z * inv; e.w = r.w * inv;
    ((float4*)ne)[idx] = e;
}

extern "C" void kernel_launch(void* const* d_in, const int* in_sizes, int n_in,
                              void* d_out, int out_size, void* d_ws, size_t ws_size,
                              hipStream_t stream) {
    const float* x     = (const float*)d_in[0];
    const float* embed = (const float*)d_in[1];
    const float* cs    = (const float*)d_in[2];
    const float* ea    = (const float*)d_in[3];

    float* out     = (float*)d_out;
    float* o_quant = out;
    float* o_ind   = o_quant + (size_t)Nn * Dd;
    float* o_dist  = o_ind + Nn;
    float* o_ncs   = o_dist + (size_t)Nn * Kk;
    float* o_nea   = o_ncs + Kk;
    float* o_ne    = o_nea + (size_t)Kk * Dd;

    // ---- ws layout (regions sized for 3 planes; interleaved uses 2-worth) ----
    size_t xp_elems = (size_t)3 * Nn * Dd;       // bf16
    size_t ep_elems = (size_t)3 * Kk * Dd;
    char* w = (char*)d_ws;
    unsigned short* xp = (unsigned short*)w;                 w += xp_elems * 2;
    unsigned short* epp = (unsigned short*)w;                w += ep_elems * 2;
    float* xsq   = (float*)w;                                w += (size_t)Nn * 4;
    float* esq   = (float*)w;                                w += (size_t)Kk * 4;
    int*   ind_i = (int*)w;                                  w += (size_t)Nn * 4;
    int*   bins  = (int*)w;                                  w += (size_t)Kk * 4;
    float* esum  = (float*)w;                                w += (size_t)Kk * Dd * 4;
    unsigned long long* packed = (unsigned long long*)w;     w += (size_t)Nn * 8;
    float* total = (float*)w;                                w += 256;
    size_t need = (size_t)(w - (char*)d_ws);

    if (ws_size >= need) {
        hipMemsetAsync(bins, 0, (size_t)Kk * 4 + (size_t)Kk * Dd * 4 + (size_t)Nn * 8, stream);

        conv_ilv<<<Nn / 4, 256, 0, stream>>>(x, xp, xsq);
        conv_ilv<<<Kk / 4, 256, 0, stream>>>(embed, epp, esq);

        gemm_ilv<<<(Nn / 256) * (Kk / 256), 512, 0, stream>>>(
            xp, epp, xsq, esq, o_dist, packed);

        gather_scatter_packed<<<Nn, 256, 0, stream>>>(
            x, embed, packed, o_quant, o_ind, esum, bins);
    } else {
        float* fxsq  = (float*)d_ws;
        float* fesq  = fxsq + Nn;
        int*   find  = (int*)(fesq + Kk);
        int*   fbins = find + Nn;
        float* fesum = (float*)(fbins + Kk);
        float* ftot  = fesum + (size_t)Kk * Dd;
        xsq = fxsq; esq = fesq; ind_i = find; bins = fbins; esum = fesum; total = ftot;

        hipMemsetAsync(bins, 0, (size_t)(Kk + Kk * Dd) * sizeof(float), stream);
        rows_sq<<<Nn / 4, 256, 0, stream>>>(x, xsq, Nn);
        rows_sq<<<Kk / 4, 256, 0, stream>>>(embed, esq, Kk);
        dim3 g(Nn / BM, Kk / BN);
        gemm_dist<<<g, 256, 0, stream>>>(x, embed, xsq, esq, o_dist);
        argmax_k<<<Nn / 4, 256, 0, stream>>>(o_dist, o_ind, ind_i);
        gather_scatter<<<Nn, 256, 0, stream>>>(x, embed, ind_i, o_quant, esum, bins);
    }

    finalize1<<<1, 1024, 0, stream>>>(cs, bins, o_ncs, total);
    finalize2<<<(Kk * Dd / 4) / 256, 256, 0, stream>>>(ea, esum, o_ncs, total, o_nea, o_ne);
}